// Round 2
// baseline (1120.850 us; speedup 1.0000x reference)
//
#include <hip/hip_runtime.h>
#include <hip/hip_bf16.h>

typedef __hip_bfloat16 bf16;

static __device__ __forceinline__ float b2f(bf16 v) { return __bfloat162float(v); }
static __device__ __forceinline__ bf16  f2b(float v) { return __float2bfloat16(v); }

// Shapes
#define BB     2
#define CCH    64          // DIM
#define HH_    256
#define WW_    256
#define C4_    256         // 4*DIM
#define NFULL  65536       // H*W
#define NHALF  16384       // (H/2)*(W/2)
#define SFLT   8388608     // floats per image-sized buffer (= B*C4*NHALF = B*C*H*W)

// ---------------- weight transpose: [O][I][T] (fp32) -> [T][I][O] (fp32) ----------------
__global__ void wtrans_kernel(const float* __restrict__ w, float* __restrict__ wT,
                              int O, int I, int T) {
    int idx = blockIdx.x * 256 + threadIdx.x;
    int total = O * I * T;
    if (idx >= total) return;
    int t = idx % T;
    int i = (idx / T) % I;
    int o = idx / (T * I);
    wT[((size_t)t * I + i) * O + o] = w[idx];
}

__global__ void zero_scr_kernel(float* __restrict__ scr) {
    for (int i = threadIdx.x; i < 4864; i += 256) scr[i] = 0.f;
}

// ---------------- Haar DWT: x (fp32, B,64,256,256) -> D0 (fp32, B,256,128,128) ----------
// D0 channels: [lh(0..63), hl(64..127), hh(128..191), ll(192..255)]
__global__ void dwt_kernel(const float* __restrict__ x, float* __restrict__ d0) {
    int idx = blockIdx.x * 256 + threadIdx.x;   // B*64*128*128 threads
    int xc = idx & 127;
    int y  = (idx >> 7) & 127;
    int c  = (idx >> 14) & 63;
    int b  = idx >> 20;
    const float* xp = x + ((size_t)(b * CCH + c) * HH_ + 2 * y) * WW_ + 2 * xc;
    float a  = xp[0];
    float bb = xp[1];
    float cc = xp[WW_];
    float dd = xp[WW_ + 1];
    float ll = (a + bb + cc + dd) * 0.5f;
    float lh = (a - bb + cc - dd) * 0.5f;
    float hl = (a + bb - cc - dd) * 0.5f;
    float hh = (a - bb - cc + dd) * 0.5f;
    size_t base = (size_t)b * C4_ * NHALF + (size_t)y * 128 + xc;
    d0[base + (size_t)(c      ) * NHALF] = lh;
    d0[base + (size_t)(c +  64) * NHALF] = hl;
    d0[base + (size_t)(c + 128) * NHALF] = hh;
    d0[base + (size_t)(c + 192) * NHALF] = ll;
}

// ---------------- Haar IDWT shuffle: D1 (B,256,128,128) -> I0 (B,64,256,256) ------------
// group channel 4c+0=yl, 4c+1=lh, 4c+2=hl, 4c+3=hh
__global__ void idwt_kernel(const float* __restrict__ d1, float* __restrict__ i0) {
    int idx = blockIdx.x * 256 + threadIdx.x;   // B*64*128*128 threads
    int xc = idx & 127;
    int y  = (idx >> 7) & 127;
    int c  = (idx >> 14) & 63;
    int b  = idx >> 20;
    const float* p = d1 + ((size_t)(b * C4_ + 4 * c)) * NHALF + (size_t)y * 128 + xc;
    float yl = p[0];
    float lh = p[NHALF];
    float hl = p[2 * NHALF];
    float hh = p[3 * NHALF];
    float a_ = (yl + lh + hl + hh) * 0.5f;
    float b_ = (yl - lh + hl - hh) * 0.5f;
    float c_ = (yl + lh - hl - hh) * 0.5f;
    float d_ = (yl - lh - hl + hh) * 0.5f;
    float* o = i0 + ((size_t)(b * CCH + c) * HH_ + 2 * y) * WW_ + 2 * xc;
    o[0] = a_; o[1] = b_; o[WW_] = c_; o[WW_ + 1] = d_;
}

__device__ __forceinline__ void outer4(float (&acc)[4][4], float4 av, float4 bv) {
    acc[0][0] += av.x * bv.x; acc[0][1] += av.x * bv.y; acc[0][2] += av.x * bv.z; acc[0][3] += av.x * bv.w;
    acc[1][0] += av.y * bv.x; acc[1][1] += av.y * bv.y; acc[1][2] += av.y * bv.z; acc[1][3] += av.y * bv.w;
    acc[2][0] += av.z * bv.x; acc[2][1] += av.z * bv.y; acc[2][2] += av.z * bv.z; acc[2][3] += av.z * bv.w;
    acc[3][0] += av.w * bv.x; acc[3][1] += av.w * bv.y; acc[3][2] += av.w * bv.z; acc[3][3] += av.w * bv.w;
}

// ---------------- 3x3 conv, reflect pad 1, leaky relu 0.01; Cin=Cout=C ------------------
// in fp32 [B][C][H][W]; wT fp32 [tap][ci][oc]; bias fp32 [C]; out fp32
// grid: (C/64, H*W/64, B); block 256
__global__ __launch_bounds__(256) void conv3x3_kernel(
        const float* __restrict__ in, const float* __restrict__ wT,
        const float* __restrict__ bias, float* __restrict__ out,
        int C, int H, int W) {
    __shared__ __align__(16) float As[16][64];
    __shared__ __align__(16) float Bs[16][64];
    int tid = threadIdx.x;
    int tx = tid & 15, ty = tid >> 4;
    int oc0 = blockIdx.x << 6;
    int wtiles = W >> 6;
    int y  = blockIdx.y / wtiles;
    int x0 = (blockIdx.y % wtiles) << 6;
    int b = blockIdx.z;
    const float* inb = in + (size_t)b * C * H * W;

    float acc[4][4];
    for (int i = 0; i < 4; ++i) {
        float bv = bias[oc0 + ty * 4 + i];
        for (int j = 0; j < 4; ++j) acc[i][j] = bv;
    }

    for (int tap = 0; tap < 9; ++tap) {
        int di = tap / 3 - 1, dj = tap % 3 - 1;
        int r = y + di;
        if (r < 0) r = -r; else if (r >= H) r = 2 * H - 2 - r;
        const float* inrow = inb + (size_t)r * W;
        for (int cic = 0; cic < C; cic += 16) {
            for (int i = 0; i < 4; ++i) {
                int idx = tid + i * 256;
                int kk = idx >> 6, e = idx & 63;
                As[kk][e] = wT[((size_t)tap * C + cic + kk) * C + oc0 + e];
                int cidx = x0 + e + dj;
                if (cidx < 0) cidx = -cidx; else if (cidx >= W) cidx = 2 * W - 2 - cidx;
                Bs[kk][e] = inrow[(size_t)(cic + kk) * H * W + cidx];
            }
            __syncthreads();
            #pragma unroll
            for (int kk = 0; kk < 16; ++kk) {
                float4 av = *reinterpret_cast<const float4*>(&As[kk][ty << 2]);
                float4 bv = *reinterpret_cast<const float4*>(&Bs[kk][tx << 2]);
                outer4(acc, av, bv);
            }
            __syncthreads();
        }
    }
    for (int i = 0; i < 4; ++i) {
        int oc = oc0 + ty * 4 + i;
        float* op = out + ((size_t)(b * C + oc) * H + y) * W + x0 + (tx << 2);
        for (int j = 0; j < 4; ++j) {
            float v = acc[i][j];
            op[j] = (v >= 0.f) ? v : 0.01f * v;
        }
    }
}

// ---------------- 1x1 conv (GEMM): out[b][co][n] = W·in + bias, out bf16 ----------------
// wT fp32 [ci][co]; grid (Cout/64, N/64, B)
__global__ __launch_bounds__(256) void conv1x1_kernel(
        const float* __restrict__ in, const float* __restrict__ wT,
        const float* __restrict__ bias, bf16* __restrict__ out,
        int Cin, int Cout, int N) {
    __shared__ __align__(16) float As[16][64];
    __shared__ __align__(16) float Bs[16][64];
    int tid = threadIdx.x;
    int tx = tid & 15, ty = tid >> 4;
    int oc0 = blockIdx.x << 6;
    int n0  = blockIdx.y << 6;
    int b = blockIdx.z;
    const float* inb = in + (size_t)b * Cin * N;

    float acc[4][4];
    for (int i = 0; i < 4; ++i) {
        float bv = bias[oc0 + ty * 4 + i];
        for (int j = 0; j < 4; ++j) acc[i][j] = bv;
    }
    for (int cic = 0; cic < Cin; cic += 16) {
        for (int i = 0; i < 4; ++i) {
            int idx = tid + i * 256;
            int kk = idx >> 6, e = idx & 63;
            As[kk][e] = wT[(size_t)(cic + kk) * Cout + oc0 + e];
            Bs[kk][e] = inb[(size_t)(cic + kk) * N + n0 + e];
        }
        __syncthreads();
        #pragma unroll
        for (int kk = 0; kk < 16; ++kk) {
            float4 av = *reinterpret_cast<const float4*>(&As[kk][ty << 2]);
            float4 bv = *reinterpret_cast<const float4*>(&Bs[kk][tx << 2]);
            outer4(acc, av, bv);
        }
        __syncthreads();
    }
    for (int i = 0; i < 4; ++i) {
        int oc = oc0 + ty * 4 + i;
        bf16* op = out + (size_t)(b * Cout + oc) * N + n0 + (tx << 2);
        for (int j = 0; j < 4; ++j) op[j] = f2b(acc[i][j]);
    }
}

// ---------------- Gram + squared-norm reduction over n ----------------------------------
// Q,K bf16 [B][64][65536] (K is the flat view of the conv output — reshape is free)
// gram[b][h][c][d] = sum_n Q[h*16+c][n]*K[h*16+d][n]; qss/kss = row sum of squares
__global__ __launch_bounds__(256) void gram_kernel(
        const bf16* __restrict__ Q, const bf16* __restrict__ K,
        float* __restrict__ qss, float* __restrict__ kss, float* __restrict__ gram) {
    __shared__ float Qs[64][65];
    __shared__ float Ks[64][65];
    int tid = threadIdx.x;
    int b = blockIdx.y;
    int chunk0 = blockIdx.x * 256;
    float accg[4] = {0.f, 0.f, 0.f, 0.f};
    float accq = 0.f, acck = 0.f;
    for (int t = 0; t < 4; ++t) {
        int n0 = chunk0 + t * 64;
        for (int i = 0; i < 16; ++i) {
            int idx = tid + i * 256;
            int ch = idx >> 6, px = idx & 63;
            Qs[ch][px] = b2f(Q[((size_t)b * 64 + ch) * NFULL + n0 + px]);
            Ks[ch][px] = b2f(K[((size_t)b * 64 + ch) * NFULL + n0 + px]);
        }
        __syncthreads();
        for (int px = 0; px < 64; ++px) {
            #pragma unroll
            for (int j = 0; j < 4; ++j) {
                int e = tid + j * 256;             // e = h*256 + c*16 + d
                int rq = e >> 4;                    // h*16+c  (e<1024 so rq<64)
                int rk = ((e >> 8) << 4) | (e & 15);// h*16+d
                accg[j] += Qs[rq & 63][px] * Ks[rk][px];
            }
            if (tid < 64) { accq += Qs[tid][px] * Qs[tid][px]; }
            else if (tid < 128) { int ch = tid - 64; acck += Ks[ch][px] * Ks[ch][px]; }
        }
        __syncthreads();
    }
    for (int j = 0; j < 4; ++j) atomicAdd(&gram[b * 1024 + tid + j * 256], accg[j]);
    if (tid < 64) atomicAdd(&qss[b * 64 + tid], accq);
    else if (tid < 128) atomicAdd(&kss[b * 64 + tid - 64], acck);
}

// ---------------- softmax(cos-sim * temp) per (b,h) -------------------------------------
__global__ void attn_kernel(const float* __restrict__ gram, const float* __restrict__ qss,
                            const float* __restrict__ kss, const float* __restrict__ temp,
                            float* __restrict__ attn) {
    int bh = blockIdx.x;
    int b = bh >> 2, h = bh & 3;
    int tid = threadIdx.x;              // 256 = 16x16
    __shared__ float L[16][17];
    __shared__ float rowmax[16], rowsum[16];
    int c = tid >> 4, d = tid & 15;
    float qn = fmaxf(sqrtf(qss[b * 64 + h * 16 + c]), 1e-12f);
    float kn = fmaxf(sqrtf(kss[b * 64 + h * 16 + d]), 1e-12f);
    float lg = gram[b * 1024 + h * 256 + c * 16 + d] / (qn * kn) * temp[h];
    L[c][d] = lg;
    __syncthreads();
    if (tid < 16) {
        float m = -1e30f;
        for (int j = 0; j < 16; ++j) m = fmaxf(m, L[tid][j]);
        rowmax[tid] = m;
    }
    __syncthreads();
    float e = expf(lg - rowmax[c]);
    L[c][d] = e;
    __syncthreads();
    if (tid < 16) {
        float s = 0.f;
        for (int j = 0; j < 16; ++j) s += L[tid][j];
        rowsum[tid] = s;
    }
    __syncthreads();
    attn[b * 1024 + h * 256 + c * 16 + d] = e / rowsum[c];
}

// ---------------- fold attn into V-weights and the output projection --------------------
// WfoldT[b][t][ci][co] = sum_C Wp1[co][C] * sum_d attn[b,h(C),c(C),d] * W3[4*(h*16+d)+t][ci]
// bfold[b][t][co]      = sum_C Wp1[co][C] * sum_d attn[...] * b3[4*(h*16+d)+t]
// grid: 8 blocks (b*4+t), 256 threads
__global__ __launch_bounds__(256) void fold_kernel(
        const float* __restrict__ attn, const float* __restrict__ w3,
        const float* __restrict__ b3, const float* __restrict__ wproj,
        float* __restrict__ WfoldT, float* __restrict__ bfold) {
    int bt = blockIdx.x;
    int b = bt >> 2, t = bt & 3;
    int tid = threadIdx.x;
    __shared__ float attn_s[1024];
    __shared__ float Aeff[64][256];
    __shared__ float beff[64];
    for (int i = 0; i < 4; ++i) attn_s[tid + i * 256] = attn[b * 1024 + tid + i * 256];
    __syncthreads();
    // Aeff[C][j=tid] = sum_d attn[h,c,d] * W3[4*(h*16+d)+t][tid]
    for (int C = 0; C < 64; ++C) {
        int h = C >> 4, c = C & 15;
        float s = 0.f;
        for (int d = 0; d < 16; ++d)
            s += attn_s[h * 256 + c * 16 + d] * w3[(size_t)(4 * (h * 16 + d) + t) * 256 + tid];
        Aeff[C][tid] = s;
    }
    if (tid < 64) {
        int h = tid >> 4, c = tid & 15;
        float s = 0.f;
        for (int d = 0; d < 16; ++d)
            s += attn_s[h * 256 + c * 16 + d] * b3[4 * (h * 16 + d) + t];
        beff[tid] = s;
    }
    __syncthreads();
    // WfoldT[bt][ci=tid][co] = sum_C wproj[co][C] * Aeff[C][tid]
    for (int co = 0; co < 64; ++co) {
        float wsum = 0.f;
        for (int C = 0; C < 64; ++C) wsum += wproj[co * 128 + C] * Aeff[C][tid];
        WfoldT[((size_t)bt * 256 + tid) * 64 + co] = wsum;
    }
    if (tid < 64) {
        float s = 0.f;
        for (int C = 0; C < 64; ++C) s += wproj[tid * 128 + C] * beff[C];
        bfold[bt * 64 + tid] = s;
    }
}

// ---------------- final: out = Wfold[b,t]·x_dwt(m) + bfold + Wp2·x_idwt(n), fp32 --------
// grid (1, 1024, 2); n0 = blockIdx.y*64; t = n0>>14; m0 = n0 & 16383
// NOTE: I2 aliases `out` (d_out). Safe: each block reads I2 only at its own
// (b, n-column) range and all reads complete before its stores; blocks are
// disjoint in (b, n0).
__global__ __launch_bounds__(256) void final_kernel(
        const float* __restrict__ D1, const float* __restrict__ I2,
        const float* __restrict__ WfoldT, const float* __restrict__ bfold,
        const float* __restrict__ wpT, float* __restrict__ out) {
    __shared__ __align__(16) float As[16][64];
    __shared__ __align__(16) float Bs[16][64];
    int tid = threadIdx.x;
    int tx = tid & 15, ty = tid >> 4;
    int b = blockIdx.z;
    int n0 = blockIdx.y << 6;
    int t = n0 >> 14;
    int m0 = n0 & 16383;
    int bt = b * 4 + t;

    float acc[4][4];
    for (int i = 0; i < 4; ++i) {
        float bv = bfold[bt * 64 + ty * 4 + i];
        for (int j = 0; j < 4; ++j) acc[i][j] = bv;
    }
    // part 1: K=256 over x_dwt (D1) with folded attn·V·proj weight
    for (int cic = 0; cic < 256; cic += 16) {
        for (int i = 0; i < 4; ++i) {
            int idx = tid + i * 256;
            int kk = idx >> 6, e = idx & 63;
            As[kk][e] = WfoldT[((size_t)bt * 256 + cic + kk) * 64 + e];
            Bs[kk][e] = D1[((size_t)(b * 256 + cic + kk)) * NHALF + m0 + e];
        }
        __syncthreads();
        #pragma unroll
        for (int kk = 0; kk < 16; ++kk) {
            float4 av = *reinterpret_cast<const float4*>(&As[kk][ty << 2]);
            float4 bv = *reinterpret_cast<const float4*>(&Bs[kk][tx << 2]);
            outer4(acc, av, bv);
        }
        __syncthreads();
    }
    // part 2: K=64 over x_idwt (I2) with Wp2 (wpT rows 64..127)
    for (int cic = 0; cic < 64; cic += 16) {
        for (int i = 0; i < 4; ++i) {
            int idx = tid + i * 256;
            int kk = idx >> 6, e = idx & 63;
            As[kk][e] = wpT[(size_t)(64 + cic + kk) * 64 + e];
            Bs[kk][e] = I2[((size_t)(b * 64 + cic + kk)) * NFULL + n0 + e];
        }
        __syncthreads();
        #pragma unroll
        for (int kk = 0; kk < 16; ++kk) {
            float4 av = *reinterpret_cast<const float4*>(&As[kk][ty << 2]);
            float4 bv = *reinterpret_cast<const float4*>(&Bs[kk][tx << 2]);
            outer4(acc, av, bv);
        }
        __syncthreads();
    }
    for (int i = 0; i < 4; ++i) {
        int oc = ty * 4 + i;
        float* op = out + (size_t)(b * 64 + oc) * NFULL + n0 + (tx << 2);
        for (int j = 0; j < 4; ++j) op[j] = acc[i][j];
    }
}

extern "C" void kernel_launch(void* const* d_in, const int* in_sizes, int n_in,
                              void* d_out, int out_size, void* d_ws, size_t ws_size,
                              hipStream_t stream) {
    const float* x     = (const float*)d_in[0];
    const float* temp  = (const float*)d_in[1];
    const float* w1    = (const float*)d_in[2];
    const float* b1    = (const float*)d_in[3];
    const float* w2    = (const float*)d_in[4];
    const float* b2    = (const float*)d_in[5];
    const float* w3    = (const float*)d_in[6];
    const float* b3    = (const float*)d_in[7];
    const float* wdwt  = (const float*)d_in[8];
    const float* bdwt  = (const float*)d_in[9];
    const float* widwt = (const float*)d_in[10];
    const float* bidwt = (const float*)d_in[11];
    const float* wproj = (const float*)d_in[12];
    float* out = (float*)d_out;

    // Workspace layout (floats):
    //   slot0 [0 .. SFLT)           : D0 -> I0 -> {Qb, Kb} (bf16, 2 x 4194304 floats)
    //   slot1 [SFLT .. 2*SFLT)      : D1 (x_dwt post conv+leaky)
    //   scr   [2*SFLT .. +840448)   : stats + transposed weights
    // I2 (x_idwt post conv+leaky) lives in d_out (exact size match; see final_kernel note)
    float* wsf = (float*)d_ws;
    float* D0 = wsf;
    float* I0 = wsf;
    float* D1 = wsf + SFLT;
    float* I2 = out;
    float* scr = wsf + 2 * (size_t)SFLT;
    float* qss    = scr;
    float* kss    = scr + 128;
    float* gram   = scr + 256;
    float* attn   = scr + 2304;
    float* bfold  = scr + 4352;
    float* WfoldT = scr + 4864;
    float* w1T    = scr + 135936;
    float* w2T    = scr + 140032;
    float* wdT    = scr + 205568;
    float* wiT    = scr + 795392;
    float* wpT    = scr + 832256;
    bf16* Qb = (bf16*)wsf;                         // 16.78 MB
    bf16* Kb = (bf16*)(wsf + 4194304);             // 16.78 MB

    // weight transposes (coalesced GEMM staging)
    wtrans_kernel<<<(64 * 64 + 255) / 256, 256, 0, stream>>>(w1, w1T, 64, 64, 1);
    wtrans_kernel<<<(256 * 256 + 255) / 256, 256, 0, stream>>>(w2, w2T, 256, 256, 1);
    wtrans_kernel<<<(256 * 256 * 9 + 255) / 256, 256, 0, stream>>>(wdwt, wdT, 256, 256, 9);
    wtrans_kernel<<<(64 * 64 * 9 + 255) / 256, 256, 0, stream>>>(widwt, wiT, 64, 64, 9);
    wtrans_kernel<<<(64 * 128 + 255) / 256, 256, 0, stream>>>(wproj, wpT, 64, 128, 1);
    zero_scr_kernel<<<1, 256, 0, stream>>>(scr);

    // DWT branch
    dwt_kernel<<<8192, 256, 0, stream>>>(x, D0);
    conv3x3_kernel<<<dim3(4, 256, 2), 256, 0, stream>>>(D0, wdT, bdwt, D1, 256, 128, 128);

    // IDWT branch (I2 staged in d_out)
    idwt_kernel<<<8192, 256, 0, stream>>>(D1, I0);
    conv3x3_kernel<<<dim3(1, 1024, 2), 256, 0, stream>>>(I0, wiT, bidwt, I2, 64, 256, 256);

    // Q / K as bf16 (K stored in conv layout == flat reshaped view)
    conv1x1_kernel<<<dim3(1, 1024, 2), 256, 0, stream>>>(x, w1T, b1, Qb, 64, 64, NFULL);
    conv1x1_kernel<<<dim3(4, 256, 2), 256, 0, stream>>>(D1, w2T, b2, Kb, 256, 256, NHALF);

    // attention stats -> softmax -> fold into final weights
    gram_kernel<<<dim3(256, 2), 256, 0, stream>>>(Qb, Kb, qss, kss, gram);
    attn_kernel<<<8, 256, 0, stream>>>(gram, qss, kss, temp, attn);
    fold_kernel<<<8, 256, 0, stream>>>(attn, w3, b3, wproj, WfoldT, bfold);

    // fused (attn·V + proj) + idwt-branch proj
    final_kernel<<<dim3(1, 1024, 2), 256, 0, stream>>>(D1, I2, WfoldT, bfold, wpT, out);
}

// Round 3
// 421.977 us; speedup vs baseline: 2.6562x; 2.6562x over previous
//
#include <hip/hip_runtime.h>
#include <hip/hip_bf16.h>

typedef __hip_bfloat16 bf16;
typedef __attribute__((ext_vector_type(8))) short short8;
typedef __attribute__((ext_vector_type(4))) float f32x4;
typedef unsigned short u16;
typedef unsigned int u32;

static __device__ __forceinline__ float b2f(bf16 v) { return __bfloat162float(v); }
static __device__ __forceinline__ bf16  f2b(float v) { return __float2bfloat16(v); }
static __device__ __forceinline__ u16 f2bs(float f) {
    bf16 h = __float2bfloat16(f);
    return *reinterpret_cast<u16*>(&h);
}
static __device__ __forceinline__ float bs2f(u16 u) {
    union { float f; u32 i; } x; x.i = ((u32)u) << 16; return x.f;
}
static __device__ __forceinline__ uint4 pack8(const u16* p) {
    uint4 v;
    v.x = (u32)p[0] | ((u32)p[1] << 16);
    v.y = (u32)p[2] | ((u32)p[3] << 16);
    v.z = (u32)p[4] | ((u32)p[5] << 16);
    v.w = (u32)p[6] | ((u32)p[7] << 16);
    return v;
}

// =================== weight prep: fp32 -> bf16 A-fragment order ===================
// conv3x3 weights w[O][I][3][3] -> wF[(ocblk*nchunks+ch)*5 + pair][mt][lane][8]
// k-slot s = (lane>>4)*8 + j in [0,32): tap = 2*pair + (s>>4) (zero-pad tap 9), ci = ch*16 + (s&15)
__global__ void prep3_kernel(const float* __restrict__ w, short* __restrict__ wF,
                             int C, int nchunks) {
    int idx = blockIdx.x * 256 + threadIdx.x;
    int total = (C / 64) * nchunks * 10240;
    if (idx >= total) return;
    int j = idx & 7;
    int lane = (idx >> 3) & 63;
    int mt = (idx >> 9) & 3;
    int rest = idx >> 11;
    int pair = rest % 5;
    int bo = rest / 5;
    int ch = bo % nchunks;
    int ocblk = bo / nchunks;
    int s = ((lane >> 4) * 8 + j);
    int tp = 2 * pair + (s >> 4);
    int ci = ch * 16 + (s & 15);
    int oc = ocblk * 64 + mt * 16 + (lane & 15);
    float v = (tp <= 8) ? w[((size_t)(oc * C + ci)) * 9 + tp] : 0.f;
    wF[idx] = (short)f2bs(v);
}

// 1x1 weights w[O][Cin] -> wF[(ocblk*nchunks+ch)][mt][lane][8], ci-chunk 32: ci = cioff + ch*32 + s
__global__ void prep1_kernel(const float* __restrict__ w, short* __restrict__ wF,
                             int Cin, int cioff, int ocblks, int nchunks) {
    int idx = blockIdx.x * 256 + threadIdx.x;
    int total = ocblks * nchunks * 2048;
    if (idx >= total) return;
    int j = idx & 7;
    int lane = (idx >> 3) & 63;
    int mt = (idx >> 9) & 3;
    int bo = idx >> 11;
    int ch = bo % nchunks;
    int ocblk = bo / nchunks;
    int s = (lane >> 4) * 8 + j;
    int ci = cioff + ch * 32 + s;
    int oc = ocblk * 64 + mt * 16 + (lane & 15);
    wF[idx] = (short)f2bs(w[(size_t)oc * Cin + ci]);
}

// fp32 transpose [O][I] -> [I][O]  (for the VALU Q conv)
__global__ void wtrans_kernel(const float* __restrict__ w, float* __restrict__ wT,
                              int O, int I, int T) {
    int idx = blockIdx.x * 256 + threadIdx.x;
    int total = O * I * T;
    if (idx >= total) return;
    int t = idx % T;
    int i = (idx / T) % I;
    int o = idx / (T * I);
    wT[((size_t)t * I + i) * O + o] = w[idx];
}

__global__ void zero_scr_kernel(float* __restrict__ scr) {
    for (int i = threadIdx.x; i < 4864; i += 256) scr[i] = 0.f;
}

// =================== Haar DWT: x fp32 [b][64][256][256] -> D0 bf16 channels-last ===================
// D0[b][y][x2][ci]: ci = g*64 + c, groups: 0=lh 1=hl 2=hh 3=ll. grid (2 c-chunk, 128 y, 2 b)
__global__ __launch_bounds__(256) void dwt_kernel(const float* __restrict__ x, short* __restrict__ d0) {
    __shared__ u16 Xs[32][2][256];
    int cc = blockIdx.x;
    int y = blockIdx.y;
    int b = blockIdx.z;
    int tid = threadIdx.x;
    int c = tid >> 3;
    int xo = tid & 7;
    const float* xb = x + ((size_t)((b * 64 + cc * 32 + c) * 256 + 2 * y)) * 256;
    for (int r = 0; r < 2; ++r) {
        const float* row = xb + r * 256;
        #pragma unroll
        for (int k = 0; k < 8; ++k) {
            int xx = xo * 32 + k * 4;
            float4 v = *(const float4*)(row + xx);
            uint2 pk;
            pk.x = (u32)f2bs(v.x) | ((u32)f2bs(v.y) << 16);
            pk.y = (u32)f2bs(v.z) | ((u32)f2bs(v.w) << 16);
            *(uint2*)&Xs[c][r][xx] = pk;
        }
    }
    __syncthreads();
    int px = tid >> 1;
    int half = tid & 1;
    u16 obuf[4][16];
    #pragma unroll
    for (int ci = 0; ci < 16; ++ci) {
        int cl = half * 16 + ci;
        float a = bs2f(Xs[cl][0][2 * px]);
        float bb = bs2f(Xs[cl][0][2 * px + 1]);
        float c2 = bs2f(Xs[cl][1][2 * px]);
        float dd = bs2f(Xs[cl][1][2 * px + 1]);
        obuf[0][ci] = f2bs((a - bb + c2 - dd) * 0.5f);  // lh
        obuf[1][ci] = f2bs((a + bb - c2 - dd) * 0.5f);  // hl
        obuf[2][ci] = f2bs((a - bb - c2 + dd) * 0.5f);  // hh
        obuf[3][ci] = f2bs((a + bb + c2 + dd) * 0.5f);  // ll
    }
    size_t P = ((size_t)(b * 128 + y) * 128 + px) * 256;
    for (int g = 0; g < 4; ++g) {
        *(uint4*)&d0[P + g * 64 + cc * 32 + half * 16] = pack8(&obuf[g][0]);
        *(uint4*)&d0[P + g * 64 + cc * 32 + half * 16 + 8] = pack8(&obuf[g][8]);
    }
}

// =================== Haar IDWT: D1 bf16 cl [b][m][256] -> I0 bf16 cl [b][Y][X][64] ===================
// D1 channel 4c+t: t=0 yl, 1 lh, 2 hl, 3 hh. wave = 64 channels of one dwt-pixel.
__global__ __launch_bounds__(256) void idwt_kernel(const short* __restrict__ d1, short* __restrict__ i0) {
    int tid = threadIdx.x;
    int lane = tid & 63;
    int p = blockIdx.x * 4 + (tid >> 6);
    int b = p >> 14, m = p & 16383;
    ushort4 v = *(const ushort4*)(d1 + ((size_t)(b * 16384 + m)) * 256 + 4 * lane);
    float yl = bs2f(v.x), lh = bs2f(v.y), hl = bs2f(v.z), hh = bs2f(v.w);
    float a_ = (yl + lh + hl + hh) * 0.5f;
    float b_ = (yl - lh + hl - hh) * 0.5f;
    float c_ = (yl + lh - hl - hh) * 0.5f;
    float d_ = (yl - lh - hl + hh) * 0.5f;
    int y = m >> 7, xx = m & 127;
    u16* o = (u16*)i0;
    size_t base = ((size_t)(b * 256 + 2 * y) * 256 + 2 * xx) * 64 + lane;
    o[base] = f2bs(a_);
    o[base + 64] = f2bs(b_);
    o[base + 256 * 64] = f2bs(c_);
    o[base + 256 * 64 + 64] = f2bs(d_);
}

// =================== 3x3 conv, reflect pad, leaky 0.01, MFMA implicit GEMM ===================
// in bf16 cl [b][H][W][C]; wF frag-order; bias fp32; out bf16 cl.
// block 64oc x 256px (rpt rows of W); 4 waves of 64x64. K = (tap-pairs, ci16).
__global__ __launch_bounds__(256) void conv3_mfma(
        const short* __restrict__ in, const short* __restrict__ wF,
        const float* __restrict__ bias, short* __restrict__ out,
        int C, int H, int W, int logW, int rpt, int nchunks) {
    __shared__ short inS[12384];
    __shared__ short wS[10240];
    int tid = threadIdx.x;
    int lane = tid & 63, wv = tid >> 6;
    int q = lane >> 4, pl = lane & 15;
    int ocblk = blockIdx.x;
    int y0 = blockIdx.y * rpt;
    int b = blockIdx.z;
    int Wp = W + 2;
    int R = rpt + 2;
    int px0w = wv * 64;

    f32x4 acc[4][4];
    for (int mt = 0; mt < 4; ++mt)
        for (int nt = 0; nt < 4; ++nt)
            acc[mt][nt] = (f32x4){0.f, 0.f, 0.f, 0.f};

    for (int ch = 0; ch < nchunks; ++ch) {
        int ci0 = ch * 16;
        for (int hr = 0; hr < R; ++hr) {
            int yy = y0 - 1 + hr;
            if (yy < 0) yy = -yy;
            if (yy >= H) yy = 2 * H - 2 - yy;
            const short* rowb = in + (((size_t)(b * H + yy)) * W) * C + ci0;
            short* dst = inS + hr * Wp * 16;
            for (int t2 = tid; t2 < Wp * 2; t2 += 256) {
                int hx = t2 >> 1, hf = t2 & 1;
                int xx = hx - 1;
                if (xx < 0) xx = 1;
                if (xx >= W) xx = W - 2;
                *(uint4*)(dst + hx * 16 + hf * 8) = *(const uint4*)(rowb + (size_t)xx * C + hf * 8);
            }
        }
        const short* wsrc = wF + ((size_t)(ocblk * nchunks + ch)) * 10240;
        for (int i = tid; i < 1280; i += 256)
            *(uint4*)(wS + i * 8) = *(const uint4*)(wsrc + i * 8);
        __syncthreads();

        for (int pr = 0; pr < 5; ++pr) {
            short8 af[4];
            #pragma unroll
            for (int mt = 0; mt < 4; ++mt)
                af[mt] = *(const short8*)(wS + ((pr * 4 + mt) * 64 + lane) * 8);
            int t1 = 2 * pr + (q >> 1);
            if (t1 > 8) t1 = 8;
            int ti = (t1 >= 6) ? 2 : ((t1 >= 3) ? 1 : 0);
            int tj = t1 - ti * 3;
            #pragma unroll
            for (int nt = 0; nt < 4; ++nt) {
                int n = px0w + nt * 16 + pl;
                int rl = n >> logW, xl = n & (W - 1);
                short8 bfr = *(const short8*)(inS + ((rl + ti) * Wp + xl + tj) * 16 + (q & 1) * 8);
                #pragma unroll
                for (int mt = 0; mt < 4; ++mt)
                    acc[mt][nt] = __builtin_amdgcn_mfma_f32_16x16x32_bf16(af[mt], bfr, acc[mt][nt], 0, 0, 0);
            }
        }
        __syncthreads();
    }

    for (int mt = 0; mt < 4; ++mt) {
        int ocb = ocblk * 64 + mt * 16 + q * 4;
        float4 bi = *(const float4*)(bias + ocb);
        float bia[4] = {bi.x, bi.y, bi.z, bi.w};
        for (int nt = 0; nt < 4; ++nt) {
            int n = px0w + nt * 16 + pl;
            int rl = n >> logW, xl = n & (W - 1);
            ushort4 pk;
            float v0 = acc[mt][nt][0] + bia[0]; pk.x = f2bs(v0 >= 0.f ? v0 : 0.01f * v0);
            float v1 = acc[mt][nt][1] + bia[1]; pk.y = f2bs(v1 >= 0.f ? v1 : 0.01f * v1);
            float v2 = acc[mt][nt][2] + bia[2]; pk.z = f2bs(v2 >= 0.f ? v2 : 0.01f * v2);
            float v3 = acc[mt][nt][3] + bia[3]; pk.w = f2bs(v3 >= 0.f ? v3 : 0.01f * v3);
            *(ushort4*)(out + (((size_t)(b * H + y0 + rl)) * W + xl) * C + ocb) = pk;
        }
    }
}

// =================== K conv 1x1 MFMA: D1cl -> Kb bf16 channel-major flat view ===================
// out Kb[b][64][65536]: co -> ch=co>>2, n = (co&3)*16384 + m. grid (4, 64, 2)
__global__ __launch_bounds__(256) void kconv_mfma(
        const short* __restrict__ in, const short* __restrict__ wF,
        const float* __restrict__ bias, short* __restrict__ outK) {
    __shared__ short inS[8192];
    __shared__ short wS[2048];
    int tid = threadIdx.x;
    int lane = tid & 63, wv = tid >> 6;
    int q = lane >> 4, pl = lane & 15;
    int ocblk = blockIdx.x;
    int m0 = blockIdx.y * 256;
    int b = blockIdx.z;
    int px0w = wv * 64;
    f32x4 acc[4][4];
    for (int mt = 0; mt < 4; ++mt)
        for (int nt = 0; nt < 4; ++nt)
            acc[mt][nt] = (f32x4){0.f, 0.f, 0.f, 0.f};

    for (int ch = 0; ch < 8; ++ch) {
        const short* src = in + ((size_t)(b * 16384 + m0)) * 256 + ch * 32;
        for (int t = tid; t < 1024; t += 256) {
            int pix = t >> 2, hf = t & 3;
            *(uint4*)(inS + pix * 32 + hf * 8) = *(const uint4*)(src + (size_t)pix * 256 + hf * 8);
        }
        const short* wsrc = wF + ((size_t)(ocblk * 8 + ch)) * 2048;
        *(uint4*)(wS + tid * 8) = *(const uint4*)(wsrc + tid * 8);
        __syncthreads();
        short8 af[4];
        #pragma unroll
        for (int mt = 0; mt < 4; ++mt)
            af[mt] = *(const short8*)(wS + (mt * 64 + lane) * 8);
        #pragma unroll
        for (int nt = 0; nt < 4; ++nt) {
            int n = px0w + nt * 16 + pl;
            short8 bfr = *(const short8*)(inS + n * 32 + q * 8);
            #pragma unroll
            for (int mt = 0; mt < 4; ++mt)
                acc[mt][nt] = __builtin_amdgcn_mfma_f32_16x16x32_bf16(af[mt], bfr, acc[mt][nt], 0, 0, 0);
        }
        __syncthreads();
    }
    for (int mt = 0; mt < 4; ++mt) {
        int ocb = ocblk * 64 + mt * 16 + q * 4;
        float4 bi = *(const float4*)(bias + ocb);
        float bia[4] = {bi.x, bi.y, bi.z, bi.w};
        for (int nt = 0; nt < 4; ++nt) {
            int n = m0 + px0w + nt * 16 + pl;
            #pragma unroll
            for (int r = 0; r < 4; ++r) {
                int co = ocb + r;
                outK[((size_t)(b * 64 + (co >> 2))) * 65536 + (co & 3) * 16384 + n] =
                    (short)f2bs(acc[mt][nt][r] + bia[r]);
            }
        }
    }
}

// =================== Q conv 1x1 (VALU, fp32 x channel-major in) ===================
__global__ __launch_bounds__(256) void conv1x1_kernel(
        const float* __restrict__ in, const float* __restrict__ wT,
        const float* __restrict__ bias, bf16* __restrict__ out,
        int Cin, int Cout, int N) {
    __shared__ __align__(16) float As[16][64];
    __shared__ __align__(16) float Bs[16][64];
    int tid = threadIdx.x;
    int tx = tid & 15, ty = tid >> 4;
    int oc0 = blockIdx.x << 6;
    int n0 = blockIdx.y << 6;
    int b = blockIdx.z;
    const float* inb = in + (size_t)b * Cin * N;
    float acc[4][4];
    for (int i = 0; i < 4; ++i) {
        float bv = bias[oc0 + ty * 4 + i];
        for (int j = 0; j < 4; ++j) acc[i][j] = bv;
    }
    for (int cic = 0; cic < Cin; cic += 16) {
        for (int i = 0; i < 4; ++i) {
            int idx = tid + i * 256;
            int kk = idx >> 6, e = idx & 63;
            As[kk][e] = wT[(size_t)(cic + kk) * Cout + oc0 + e];
            Bs[kk][e] = inb[(size_t)(cic + kk) * N + n0 + e];
        }
        __syncthreads();
        #pragma unroll
        for (int kk = 0; kk < 16; ++kk) {
            float4 av = *reinterpret_cast<const float4*>(&As[kk][ty << 2]);
            float4 bv = *reinterpret_cast<const float4*>(&Bs[kk][tx << 2]);
            acc[0][0] += av.x * bv.x; acc[0][1] += av.x * bv.y; acc[0][2] += av.x * bv.z; acc[0][3] += av.x * bv.w;
            acc[1][0] += av.y * bv.x; acc[1][1] += av.y * bv.y; acc[1][2] += av.y * bv.z; acc[1][3] += av.y * bv.w;
            acc[2][0] += av.z * bv.x; acc[2][1] += av.z * bv.y; acc[2][2] += av.z * bv.z; acc[2][3] += av.z * bv.w;
            acc[3][0] += av.w * bv.x; acc[3][1] += av.w * bv.y; acc[3][2] += av.w * bv.z; acc[3][3] += av.w * bv.w;
        }
        __syncthreads();
    }
    for (int i = 0; i < 4; ++i) {
        int oc = oc0 + ty * 4 + i;
        bf16* op = out + (size_t)(b * Cout + oc) * N + n0 + (tx << 2);
        for (int j = 0; j < 4; ++j) op[j] = f2b(acc[i][j]);
    }
}

// =================== Gram + squared norms (unchanged from round 2) ===================
__global__ __launch_bounds__(256) void gram_kernel(
        const bf16* __restrict__ Q, const bf16* __restrict__ K,
        float* __restrict__ qss, float* __restrict__ kss, float* __restrict__ gram) {
    __shared__ float Qs[64][65];
    __shared__ float Ks[64][65];
    int tid = threadIdx.x;
    int b = blockIdx.y;
    int chunk0 = blockIdx.x * 256;
    float accg[4] = {0.f, 0.f, 0.f, 0.f};
    float accq = 0.f, acck = 0.f;
    for (int t = 0; t < 4; ++t) {
        int n0 = chunk0 + t * 64;
        for (int i = 0; i < 16; ++i) {
            int idx = tid + i * 256;
            int ch = idx >> 6, px = idx & 63;
            Qs[ch][px] = b2f(Q[((size_t)b * 64 + ch) * 65536 + n0 + px]);
            Ks[ch][px] = b2f(K[((size_t)b * 64 + ch) * 65536 + n0 + px]);
        }
        __syncthreads();
        for (int px = 0; px < 64; ++px) {
            #pragma unroll
            for (int j = 0; j < 4; ++j) {
                int e = tid + j * 256;
                int rq = e >> 4;
                int rk = ((e >> 8) << 4) | (e & 15);
                accg[j] += Qs[rq & 63][px] * Ks[rk][px];
            }
            if (tid < 64) { accq += Qs[tid][px] * Qs[tid][px]; }
            else if (tid < 128) { int ch = tid - 64; acck += Ks[ch][px] * Ks[ch][px]; }
        }
        __syncthreads();
    }
    for (int j = 0; j < 4; ++j) atomicAdd(&gram[b * 1024 + tid + j * 256], accg[j]);
    if (tid < 64) atomicAdd(&qss[b * 64 + tid], accq);
    else if (tid < 128) atomicAdd(&kss[b * 64 + tid - 64], acck);
}

// =================== softmax(cos-sim * temp) ===================
__global__ void attn_kernel(const float* __restrict__ gram, const float* __restrict__ qss,
                            const float* __restrict__ kss, const float* __restrict__ temp,
                            float* __restrict__ attn) {
    int bh = blockIdx.x;
    int b = bh >> 2, h = bh & 3;
    int tid = threadIdx.x;
    __shared__ float L[16][17];
    __shared__ float rowmax[16], rowsum[16];
    int c = tid >> 4, d = tid & 15;
    float qn = fmaxf(sqrtf(qss[b * 64 + h * 16 + c]), 1e-12f);
    float kn = fmaxf(sqrtf(kss[b * 64 + h * 16 + d]), 1e-12f);
    float lg = gram[b * 1024 + h * 256 + c * 16 + d] / (qn * kn) * temp[h];
    L[c][d] = lg;
    __syncthreads();
    if (tid < 16) {
        float m = -1e30f;
        for (int j = 0; j < 16; ++j) m = fmaxf(m, L[tid][j]);
        rowmax[tid] = m;
    }
    __syncthreads();
    float e = expf(lg - rowmax[c]);
    L[c][d] = e;
    __syncthreads();
    if (tid < 16) {
        float s = 0.f;
        for (int j = 0; j < 16; ++j) s += L[tid][j];
        rowsum[tid] = s;
    }
    __syncthreads();
    attn[b * 1024 + h * 256 + c * 16 + d] = e / rowsum[c];
}

// =================== fold attn into (V -> proj) weights; write A-fragment order bf16 ===================
__global__ __launch_bounds__(256) void fold_kernel(
        const float* __restrict__ attn, const float* __restrict__ w3,
        const float* __restrict__ b3, const float* __restrict__ wproj,
        short* __restrict__ WfoldF, float* __restrict__ bfold) {
    int bt = blockIdx.x;
    int b = bt >> 2, t = bt & 3;
    int tid = threadIdx.x;
    __shared__ float attn_s[1024];
    __shared__ float Aeff[64][256];
    __shared__ float beff[64];
    for (int i = 0; i < 4; ++i) attn_s[tid + i * 256] = attn[b * 1024 + tid + i * 256];
    __syncthreads();
    for (int C = 0; C < 64; ++C) {
        int h = C >> 4, c = C & 15;
        float s = 0.f;
        for (int d = 0; d < 16; ++d)
            s += attn_s[h * 256 + c * 16 + d] * w3[(size_t)(4 * (h * 16 + d) + t) * 256 + tid];
        Aeff[C][tid] = s;
    }
    if (tid < 64) {
        int h = tid >> 4, c = tid & 15;
        float s = 0.f;
        for (int d = 0; d < 16; ++d)
            s += attn_s[h * 256 + c * 16 + d] * b3[4 * (h * 16 + d) + t];
        beff[tid] = s;
    }
    __syncthreads();
    // Wfold[ci=tid][co] = sum_C wproj[co][C] * Aeff[C][tid]; scatter into A-frag order
    int chk = tid >> 5;
    int s5 = tid & 31;
    int j = s5 & 7;
    int laneq = (s5 >> 3) << 4;
    for (int co = 0; co < 64; ++co) {
        float wsum = 0.f;
        for (int C = 0; C < 64; ++C) wsum += wproj[co * 128 + C] * Aeff[C][tid];
        int lane2 = laneq | (co & 15);
        int mt = co >> 4;
        WfoldF[(((size_t)(bt * 8 + chk) * 4 + mt)) * 512 + lane2 * 8 + j] = (short)f2bs(wsum);
    }
    if (tid < 64) {
        float s = 0.f;
        for (int C = 0; C < 64; ++C) s += wproj[tid * 128 + C] * beff[C];
        bfold[bt * 64 + tid] = s;
    }
}

// =================== final: out = Wfold[b,t]·D1 + bfold + Wp2·I2, fp32 out ===================
__global__ __launch_bounds__(256) void final_mfma(
        const short* __restrict__ D1, const short* __restrict__ I2,
        const short* __restrict__ WfoldF, const short* __restrict__ wpF,
        const float* __restrict__ bfold, float* __restrict__ out) {
    __shared__ short inS[8192];
    __shared__ short wS[2048];
    int tid = threadIdx.x;
    int lane = tid & 63, wv = tid >> 6;
    int q = lane >> 4, pl = lane & 15;
    int n0 = blockIdx.x * 256;
    int b = blockIdx.y;
    int t = n0 >> 14, m0 = n0 & 16383, bt = b * 4 + t;
    int px0w = wv * 64;
    f32x4 acc[4][4];
    for (int mt = 0; mt < 4; ++mt) {
        float4 bf4 = *(const float4*)(bfold + bt * 64 + mt * 16 + q * 4);
        for (int nt = 0; nt < 4; ++nt)
            acc[mt][nt] = (f32x4){bf4.x, bf4.y, bf4.z, bf4.w};
    }
    // part 1: K=256 over D1cl
    for (int ch = 0; ch < 8; ++ch) {
        const short* src = D1 + ((size_t)(b * 16384 + m0)) * 256 + ch * 32;
        for (int tt = tid; tt < 1024; tt += 256) {
            int pix = tt >> 2, hf = tt & 3;
            *(uint4*)(inS + pix * 32 + hf * 8) = *(const uint4*)(src + (size_t)pix * 256 + hf * 8);
        }
        const short* wsrc = WfoldF + ((size_t)(bt * 8 + ch)) * 2048;
        *(uint4*)(wS + tid * 8) = *(const uint4*)(wsrc + tid * 8);
        __syncthreads();
        short8 af[4];
        #pragma unroll
        for (int mt = 0; mt < 4; ++mt)
            af[mt] = *(const short8*)(wS + (mt * 64 + lane) * 8);
        #pragma unroll
        for (int nt = 0; nt < 4; ++nt) {
            int n = px0w + nt * 16 + pl;
            short8 bfr = *(const short8*)(inS + n * 32 + q * 8);
            #pragma unroll
            for (int mt = 0; mt < 4; ++mt)
                acc[mt][nt] = __builtin_amdgcn_mfma_f32_16x16x32_bf16(af[mt], bfr, acc[mt][nt], 0, 0, 0);
        }
        __syncthreads();
    }
    // part 2: K=64 over I2cl
    for (int ch = 0; ch < 2; ++ch) {
        const short* src = I2 + ((size_t)(b * 65536 + n0)) * 64 + ch * 32;
        for (int tt = tid; tt < 1024; tt += 256) {
            int pix = tt >> 2, hf = tt & 3;
            *(uint4*)(inS + pix * 32 + hf * 8) = *(const uint4*)(src + (size_t)pix * 64 + hf * 8);
        }
        const short* wsrc = wpF + (size_t)ch * 2048;
        *(uint4*)(wS + tid * 8) = *(const uint4*)(wsrc + tid * 8);
        __syncthreads();
        short8 af[4];
        #pragma unroll
        for (int mt = 0; mt < 4; ++mt)
            af[mt] = *(const short8*)(wS + (mt * 64 + lane) * 8);
        #pragma unroll
        for (int nt = 0; nt < 4; ++nt) {
            int n = px0w + nt * 16 + pl;
            short8 bfr = *(const short8*)(inS + n * 32 + q * 8);
            #pragma unroll
            for (int mt = 0; mt < 4; ++mt)
                acc[mt][nt] = __builtin_amdgcn_mfma_f32_16x16x32_bf16(af[mt], bfr, acc[mt][nt], 0, 0, 0);
        }
        __syncthreads();
    }
    for (int mt = 0; mt < 4; ++mt) {
        for (int nt = 0; nt < 4; ++nt) {
            int n = n0 + px0w + nt * 16 + pl;
            #pragma unroll
            for (int r = 0; r < 4; ++r) {
                int co = mt * 16 + q * 4 + r;
                out[((size_t)(b * 64 + co)) * 65536 + n] = acc[mt][nt][r];
            }
        }
    }
}

extern "C" void kernel_launch(void* const* d_in, const int* in_sizes, int n_in,
                              void* d_out, int out_size, void* d_ws, size_t ws_size,
                              hipStream_t stream) {
    const float* x     = (const float*)d_in[0];
    const float* temp  = (const float*)d_in[1];
    const float* w1    = (const float*)d_in[2];
    const float* b1    = (const float*)d_in[3];
    const float* w2    = (const float*)d_in[4];
    const float* b2    = (const float*)d_in[5];
    const float* w3    = (const float*)d_in[6];
    const float* b3    = (const float*)d_in[7];
    const float* wdwt  = (const float*)d_in[8];
    const float* bdwt  = (const float*)d_in[9];
    const float* widwt = (const float*)d_in[10];
    const float* bidwt = (const float*)d_in[11];
    const float* wproj = (const float*)d_in[12];
    float* out = (float*)d_out;

    // ws layout (bytes): 4 x 16.78MB activation slots + weight preps + stats = ~69 MB
    char* W8 = (char*)d_ws;
    const size_t SLOT = 16777216;
    short* slotA = (short*)(W8);              // D0cl -> I0cl -> Qb
    short* slotB = (short*)(W8 + SLOT);       // D1cl
    short* slotC = (short*)(W8 + 2 * SLOT);   // I2cl
    short* slotD = (short*)(W8 + 3 * SLOT);   // Kb
    char* P = W8 + 4 * SLOT;
    short* wF1    = (short*)P; P += 2 * 655360;   // conv1 3x3 frag weights
    short* wF2c   = (short*)P; P += 2 * 40960;    // conv2 3x3 frag weights
    short* wFk    = (short*)P; P += 2 * 65536;    // K 1x1 frag weights
    short* wpF    = (short*)P; P += 2 * 4096;     // proj part-2 frag weights
    short* WfoldF = (short*)P; P += 2 * 131072;   // folded attn·V·proj frag weights
    float* w1T    = (float*)P; P += 4 * 4096;
    float* scr    = (float*)P;
    float* qss   = scr;
    float* kss   = scr + 128;
    float* gram  = scr + 256;
    float* attn  = scr + 2304;
    float* bfold = scr + 4352;

    // weight prep
    wtrans_kernel<<<16, 256, 0, stream>>>(w1, w1T, 64, 64, 1);
    prep3_kernel<<<2560, 256, 0, stream>>>(wdwt, wF1, 256, 16);
    prep3_kernel<<<160, 256, 0, stream>>>(widwt, wF2c, 64, 4);
    prep1_kernel<<<256, 256, 0, stream>>>(w2, wFk, 256, 0, 4, 8);
    prep1_kernel<<<16, 256, 0, stream>>>(wproj, wpF, 128, 64, 1, 2);
    zero_scr_kernel<<<1, 256, 0, stream>>>(scr);

    // DWT branch
    dwt_kernel<<<dim3(2, 128, 2), 256, 0, stream>>>(x, slotA);
    conv3_mfma<<<dim3(4, 64, 2), 256, 0, stream>>>(slotA, wF1, bdwt, slotB, 256, 128, 128, 7, 2, 16);

    // IDWT branch
    idwt_kernel<<<8192, 256, 0, stream>>>(slotB, slotA);
    conv3_mfma<<<dim3(1, 256, 2), 256, 0, stream>>>(slotA, wF2c, bidwt, slotC, 64, 256, 256, 8, 1, 4);

    // Q (VALU, x fp32 channel-major) and K (MFMA)
    conv1x1_kernel<<<dim3(1, 1024, 2), 256, 0, stream>>>(x, w1T, b1, (bf16*)slotA, 64, 64, 65536);
    kconv_mfma<<<dim3(4, 64, 2), 256, 0, stream>>>(slotB, wFk, b2, slotD);

    // attention stats -> softmax -> fold
    gram_kernel<<<dim3(256, 2), 256, 0, stream>>>((bf16*)slotA, (bf16*)slotD, qss, kss, gram);
    attn_kernel<<<8, 256, 0, stream>>>(gram, qss, kss, temp, attn);
    fold_kernel<<<8, 256, 0, stream>>>(attn, w3, b3, wproj, WfoldF, bfold);

    // fused (attn·V + proj) + idwt-branch proj
    final_mfma<<<dim3(256, 2), 256, 0, stream>>>(slotB, slotC, WfoldF, wpF, bfold, out);
}

// Round 4
// 405.410 us; speedup vs baseline: 2.7647x; 1.0409x over previous
//
#include <hip/hip_runtime.h>
#include <hip/hip_bf16.h>

typedef __hip_bfloat16 bf16;
typedef __attribute__((ext_vector_type(8))) short short8;
typedef __attribute__((ext_vector_type(4))) float f32x4;
typedef unsigned short u16;
typedef unsigned int u32;

static __device__ __forceinline__ float b2f(bf16 v) { return __bfloat162float(v); }
static __device__ __forceinline__ u16 f2bs(float f) {
    bf16 h = __float2bfloat16(f);
    return *reinterpret_cast<u16*>(&h);
}
static __device__ __forceinline__ float bs2f(u16 u) {
    union { float f; u32 i; } x; x.i = ((u32)u) << 16; return x.f;
}
static __device__ __forceinline__ uint4 pack8(const u16* p) {
    uint4 v;
    v.x = (u32)p[0] | ((u32)p[1] << 16);
    v.y = (u32)p[2] | ((u32)p[3] << 16);
    v.z = (u32)p[4] | ((u32)p[5] << 16);
    v.w = (u32)p[6] | ((u32)p[7] << 16);
    return v;
}

// =================== merged weight prep ===================
// prep3: w[O][I][3][3] -> wF[((ocblk*nch+ch)*5+pair)*4+mt][lane][8]
//   k-slot s=(lane>>4)*8+j in [0,32): tap=2*pair+(s>>4) (pad tap 9 -> 0), ci=ch*16+(s&15)
__device__ __forceinline__ void prep3_body(const float* __restrict__ w, short* __restrict__ wF,
                                           int C, int idx) {
    int j = idx & 7;
    int lane = (idx >> 3) & 63;
    int mt = (idx >> 9) & 3;
    int rest = idx >> 11;
    int pair = rest % 5;
    int bo = rest / 5;
    int nchunks = C / 16;
    int ch = bo % nchunks;
    int ocblk = bo / nchunks;
    int s = ((lane >> 4) * 8 + j);
    int tp = 2 * pair + (s >> 4);
    int ci = ch * 16 + (s & 15);
    int oc = ocblk * 64 + mt * 16 + (lane & 15);
    float v = (tp <= 8) ? w[((size_t)(oc * C + ci)) * 9 + tp] : 0.f;
    wF[idx] = (short)f2bs(v);
}
// prep1: w[O][Cin] -> wF[(ocblk*nch+ch)*4+mt][lane][8], ci = cioff + ch*32 + (lane>>4)*8+j
__device__ __forceinline__ void prep1_body(const float* __restrict__ w, short* __restrict__ wF,
                                           int Cin, int cioff, int nchunks, int idx) {
    int j = idx & 7;
    int lane = (idx >> 3) & 63;
    int mt = (idx >> 9) & 3;
    int bo = idx >> 11;
    int ch = bo % nchunks;
    int ocblk = bo / nchunks;
    int s = (lane >> 4) * 8 + j;
    int ci = cioff + ch * 32 + s;
    int oc = ocblk * 64 + mt * 16 + (lane & 15);
    wF[idx] = (short)f2bs(w[(size_t)oc * Cin + ci]);
}

__global__ __launch_bounds__(256) void prep_all(
        const float* __restrict__ wdwt, const float* __restrict__ widwt,
        const float* __restrict__ w2, const float* __restrict__ wproj,
        const float* __restrict__ w1,
        short* __restrict__ wF1, short* __restrict__ wF2c, short* __restrict__ wFk,
        short* __restrict__ wpF, short* __restrict__ wFq, float* __restrict__ scr) {
    int blk = blockIdx.x;
    int tid = threadIdx.x;
    if (blk < 2560) {
        prep3_body(wdwt, wF1, 256, blk * 256 + tid);            // 655360
    } else if (blk < 2720) {
        prep3_body(widwt, wF2c, 64, (blk - 2560) * 256 + tid);  // 40960
    } else if (blk < 2976) {
        prep1_body(w2, wFk, 256, 0, 8, (blk - 2720) * 256 + tid);   // 65536
    } else if (blk < 2992) {
        prep1_body(wproj, wpF, 128, 64, 2, (blk - 2976) * 256 + tid); // 4096
    } else if (blk < 3008) {
        prep1_body(w1, wFq, 64, 0, 2, (blk - 2992) * 256 + tid);      // 4096
    } else {
        for (int i = tid; i < 4864; i += 256) scr[i] = 0.f;
    }
}

// =================== Haar DWT: x fp32 [b][64][256][256] -> D0 bf16 channels-last ===================
__global__ __launch_bounds__(256) void dwt_kernel(const float* __restrict__ x, short* __restrict__ d0) {
    __shared__ u16 Xs[32][2][256];
    int cc = blockIdx.x;
    int y = blockIdx.y;
    int b = blockIdx.z;
    int tid = threadIdx.x;
    int c = tid >> 3;
    int xo = tid & 7;
    const float* xb = x + ((size_t)((b * 64 + cc * 32 + c) * 256 + 2 * y)) * 256;
    for (int r = 0; r < 2; ++r) {
        const float* row = xb + r * 256;
        #pragma unroll
        for (int k = 0; k < 8; ++k) {
            int xx = xo * 32 + k * 4;
            float4 v = *(const float4*)(row + xx);
            uint2 pk;
            pk.x = (u32)f2bs(v.x) | ((u32)f2bs(v.y) << 16);
            pk.y = (u32)f2bs(v.z) | ((u32)f2bs(v.w) << 16);
            *(uint2*)&Xs[c][r][xx] = pk;
        }
    }
    __syncthreads();
    int px = tid >> 1;
    int half = tid & 1;
    u16 obuf[4][16];
    #pragma unroll
    for (int ci = 0; ci < 16; ++ci) {
        int cl = half * 16 + ci;
        float a = bs2f(Xs[cl][0][2 * px]);
        float bb = bs2f(Xs[cl][0][2 * px + 1]);
        float c2 = bs2f(Xs[cl][1][2 * px]);
        float dd = bs2f(Xs[cl][1][2 * px + 1]);
        obuf[0][ci] = f2bs((a - bb + c2 - dd) * 0.5f);  // lh
        obuf[1][ci] = f2bs((a + bb - c2 - dd) * 0.5f);  // hl
        obuf[2][ci] = f2bs((a - bb - c2 + dd) * 0.5f);  // hh
        obuf[3][ci] = f2bs((a + bb + c2 + dd) * 0.5f);  // ll
    }
    size_t P = ((size_t)(b * 128 + y) * 128 + px) * 256;
    for (int g = 0; g < 4; ++g) {
        *(uint4*)&d0[P + g * 64 + cc * 32 + half * 16] = pack8(&obuf[g][0]);
        *(uint4*)&d0[P + g * 64 + cc * 32 + half * 16 + 8] = pack8(&obuf[g][8]);
    }
}

// =================== Haar IDWT: D1 cl -> I0 cl [b][Y][X][64] ===================
__global__ __launch_bounds__(256) void idwt_kernel(const short* __restrict__ d1, short* __restrict__ i0) {
    int tid = threadIdx.x;
    int lane = tid & 63;
    int p = blockIdx.x * 4 + (tid >> 6);
    int b = p >> 14, m = p & 16383;
    ushort4 v = *(const ushort4*)(d1 + ((size_t)(b * 16384 + m)) * 256 + 4 * lane);
    float yl = bs2f(v.x), lh = bs2f(v.y), hl = bs2f(v.z), hh = bs2f(v.w);
    float a_ = (yl + lh + hl + hh) * 0.5f;
    float b_ = (yl - lh + hl - hh) * 0.5f;
    float c_ = (yl + lh - hl - hh) * 0.5f;
    float d_ = (yl - lh - hl + hh) * 0.5f;
    int y = m >> 7, xx = m & 127;
    u16* o = (u16*)i0;
    size_t base = ((size_t)(b * 256 + 2 * y) * 256 + 2 * xx) * 64 + lane;
    o[base] = f2bs(a_);
    o[base + 64] = f2bs(b_);
    o[base + 256 * 64] = f2bs(c_);
    o[base + 256 * 64 + 64] = f2bs(d_);
}

// =================== 3x3 conv v2: pipelined, input-only LDS, direct-global A-frags ===================
// block = 4 waves; wave w: oc-group = w/WPG, px-offset = (w%WPG)*64. tile: (OCG*64)oc x NPX px.
// grid (W/NPX, H, B). LDS: double-buffered [3][NPX+2][16] bf16 per ci16-chunk.
template <int C, int NPX, int WPG>
__global__ __launch_bounds__(256) void conv3_v2(
        const short* __restrict__ in, const short* __restrict__ wF,
        const float* __restrict__ bias, short* __restrict__ out,
        int H, int W) {
    constexpr int Wp = NPX + 2;
    constexpr int NCH = C / 16;
    constexpr int UNITS = 3 * Wp * 2;          // 16B units per chunk
    constexpr int UPT = (UNITS + 255) / 256;
    constexpr int BUFSZ = 3 * Wp * 16;         // shorts
    extern __shared__ __align__(16) short inS[];

    int tid = threadIdx.x;
    int lane = tid & 63, wv = tid >> 6;
    int q = lane >> 4, pl = lane & 15;
    int ocg = wv / WPG;
    int pxoff = (wv % WPG) * 64;
    int x0 = blockIdx.x * NPX;
    int y = blockIdx.y;
    int b = blockIdx.z;

    // staging address precompute (offsets in shorts)
    int gbase[UPT];
    int ldsoff[UPT];
    #pragma unroll
    for (int k2 = 0; k2 < UPT; ++k2) {
        int u = k2 * 256 + tid;
        if (u < UNITS) {
            int r = u / (Wp * 2);
            int rem = u - r * (Wp * 2);
            int px = rem >> 1, hf = rem & 1;
            int ry = y - 1 + r;
            if (ry < 0) ry = 1;
            if (ry >= H) ry = H - 2;
            int rx = x0 - 1 + px;
            if (rx < 0) rx = 1;
            if (rx >= W) rx = W - 2;
            gbase[k2] = ((b * H + ry) * W + rx) * C + hf * 8;
            ldsoff[k2] = (r * Wp + px) * 16 + hf * 8;
        } else { gbase[k2] = 0; ldsoff[k2] = -1; }
    }

    f32x4 acc[4][4];
    #pragma unroll
    for (int mt = 0; mt < 4; ++mt)
        #pragma unroll
        for (int nt = 0; nt < 4; ++nt)
            acc[mt][nt] = (f32x4){0.f, 0.f, 0.f, 0.f};

    // stage chunk 0
    uint4 pf[UPT];
    #pragma unroll
    for (int k2 = 0; k2 < UPT; ++k2)
        if (ldsoff[k2] >= 0) pf[k2] = *(const uint4*)(in + gbase[k2]);
    #pragma unroll
    for (int k2 = 0; k2 < UPT; ++k2)
        if (ldsoff[k2] >= 0) *(uint4*)(inS + ldsoff[k2]) = pf[k2];
    __syncthreads();

    #pragma unroll 1
    for (int ch = 0; ch < NCH; ++ch) {
        const short* buf = inS + (ch & 1) * BUFSZ;
        short* nbuf = inS + ((ch + 1) & 1) * BUFSZ;
        bool more = (ch + 1 < NCH);
        if (more) {
            #pragma unroll
            for (int k2 = 0; k2 < UPT; ++k2)
                if (ldsoff[k2] >= 0) pf[k2] = *(const uint4*)(in + gbase[k2] + (ch + 1) * 16);
        }
        const short* wbase = wF + ((size_t)(ocg * NCH + ch) * 5) * 2048;
        short8 afA[4], afB[4];
        #pragma unroll
        for (int mt = 0; mt < 4; ++mt)
            afA[mt] = *(const short8*)(wbase + mt * 512 + lane * 8);
        #pragma unroll
        for (int pr = 0; pr < 5; ++pr) {
            const short8* afc = (pr & 1) ? afB : afA;
            short8* afn = (pr & 1) ? afA : afB;
            if (pr < 4) {
                #pragma unroll
                for (int mt = 0; mt < 4; ++mt)
                    afn[mt] = *(const short8*)(wbase + ((pr + 1) * 4 + mt) * 512 + lane * 8);
            }
            int t1 = 2 * pr + (q >> 1);
            if (t1 > 8) t1 = 8;
            int ti = (t1 >= 6) ? 2 : ((t1 >= 3) ? 1 : 0);
            int tj = t1 - ti * 3;
            #pragma unroll
            for (int nt = 0; nt < 4; ++nt) {
                int i = pxoff + nt * 16 + pl + tj;
                short8 bfr = *(const short8*)(buf + (ti * Wp + i) * 16 + (q & 1) * 8);
                #pragma unroll
                for (int mt = 0; mt < 4; ++mt)
                    acc[mt][nt] = __builtin_amdgcn_mfma_f32_16x16x32_bf16(afc[mt], bfr, acc[mt][nt], 0, 0, 0);
            }
        }
        if (more) {
            #pragma unroll
            for (int k2 = 0; k2 < UPT; ++k2)
                if (ldsoff[k2] >= 0) *(uint4*)(nbuf + ldsoff[k2]) = pf[k2];
            __syncthreads();
        }
    }

    #pragma unroll
    for (int mt = 0; mt < 4; ++mt) {
        int ocb = ocg * 64 + mt * 16 + q * 4;
        float4 bi = *(const float4*)(bias + ocb);
        float bia[4] = {bi.x, bi.y, bi.z, bi.w};
        #pragma unroll
        for (int nt = 0; nt < 4; ++nt) {
            int xl = x0 + pxoff + nt * 16 + pl;
            ushort4 pk;
            float v0 = acc[mt][nt][0] + bia[0]; pk.x = f2bs(v0 >= 0.f ? v0 : 0.01f * v0);
            float v1 = acc[mt][nt][1] + bia[1]; pk.y = f2bs(v1 >= 0.f ? v1 : 0.01f * v1);
            float v2 = acc[mt][nt][2] + bia[2]; pk.z = f2bs(v2 >= 0.f ? v2 : 0.01f * v2);
            float v3 = acc[mt][nt][3] + bia[3]; pk.w = f2bs(v3 >= 0.f ? v3 : 0.01f * v3);
            *(ushort4*)(out + (((size_t)(b * H + y)) * W + xl) * C + ocb) = pk;
        }
    }
}

// =================== Q conv 1x1 MFMA: x fp32 channel-major -> Qb bf16 channel-major ===================
__global__ __launch_bounds__(256) void qconv_mfma(
        const float* __restrict__ x, const short* __restrict__ wFq,
        const float* __restrict__ bias, short* __restrict__ outQ) {
    __shared__ short inS[256 * 32];
    int tid = threadIdx.x;
    int lane = tid & 63, wv = tid >> 6;
    int q = lane >> 4, pl = lane & 15;
    int n0 = blockIdx.x * 256;
    int b = blockIdx.y;
    int pxoff = wv * 64;
    f32x4 acc[4][4];
    #pragma unroll
    for (int mt = 0; mt < 4; ++mt)
        #pragma unroll
        for (int nt = 0; nt < 4; ++nt)
            acc[mt][nt] = (f32x4){0.f, 0.f, 0.f, 0.f};

    for (int ch = 0; ch < 2; ++ch) {
        if (ch) __syncthreads();
        #pragma unroll
        for (int k2 = 0; k2 < 8; ++k2) {
            int u = k2 * 256 + tid;
            int cc = u >> 6;
            int p4 = (u & 63) * 4;
            float4 v = *(const float4*)(x + ((size_t)(b * 64 + ch * 32 + cc)) * 65536 + n0 + p4);
            inS[(p4 + 0) * 32 + cc] = (short)f2bs(v.x);
            inS[(p4 + 1) * 32 + cc] = (short)f2bs(v.y);
            inS[(p4 + 2) * 32 + cc] = (short)f2bs(v.z);
            inS[(p4 + 3) * 32 + cc] = (short)f2bs(v.w);
        }
        short8 af[4];
        #pragma unroll
        for (int mt = 0; mt < 4; ++mt)
            af[mt] = *(const short8*)(wFq + (ch * 4 + mt) * 512 + lane * 8);
        __syncthreads();
        #pragma unroll
        for (int nt = 0; nt < 4; ++nt) {
            short8 bfr = *(const short8*)(inS + (pxoff + nt * 16 + pl) * 32 + q * 8);
            #pragma unroll
            for (int mt = 0; mt < 4; ++mt)
                acc[mt][nt] = __builtin_amdgcn_mfma_f32_16x16x32_bf16(af[mt], bfr, acc[mt][nt], 0, 0, 0);
        }
    }
    #pragma unroll
    for (int mt = 0; mt < 4; ++mt) {
        int ocb = mt * 16 + q * 4;
        float4 bi = *(const float4*)(bias + ocb);
        float bia[4] = {bi.x, bi.y, bi.z, bi.w};
        #pragma unroll
        for (int nt = 0; nt < 4; ++nt) {
            int n = n0 + pxoff + nt * 16 + pl;
            #pragma unroll
            for (int r = 0; r < 4; ++r)
                outQ[((size_t)(b * 64 + ocb + r)) * 65536 + n] = (short)f2bs(acc[mt][nt][r] + bia[r]);
        }
    }
}

// =================== K conv 1x1 MFMA: D1cl -> Kb bf16 channel-major flat view ===================
__global__ __launch_bounds__(256) void kconv_mfma(
        const short* __restrict__ in, const short* __restrict__ wF,
        const float* __restrict__ bias, short* __restrict__ outK) {
    __shared__ short inS[8192];
    int tid = threadIdx.x;
    int lane = tid & 63, wv = tid >> 6;
    int q = lane >> 4, pl = lane & 15;
    int ocblk = blockIdx.x;
    int m0 = blockIdx.y * 256;
    int b = blockIdx.z;
    int px0w = wv * 64;
    f32x4 acc[4][4];
    #pragma unroll
    for (int mt = 0; mt < 4; ++mt)
        #pragma unroll
        for (int nt = 0; nt < 4; ++nt)
            acc[mt][nt] = (f32x4){0.f, 0.f, 0.f, 0.f};

    for (int ch = 0; ch < 8; ++ch) {
        if (ch) __syncthreads();
        const short* src = in + ((size_t)(b * 16384 + m0)) * 256 + ch * 32;
        for (int t = tid; t < 1024; t += 256) {
            int pix = t >> 2, hf = t & 3;
            *(uint4*)(inS + pix * 32 + hf * 8) = *(const uint4*)(src + (size_t)pix * 256 + hf * 8);
        }
        short8 af[4];
        #pragma unroll
        for (int mt = 0; mt < 4; ++mt)
            af[mt] = *(const short8*)(wF + ((size_t)(ocblk * 8 + ch)) * 2048 + mt * 512 + lane * 8);
        __syncthreads();
        #pragma unroll
        for (int nt = 0; nt < 4; ++nt) {
            short8 bfr = *(const short8*)(inS + (px0w + nt * 16 + pl) * 32 + q * 8);
            #pragma unroll
            for (int mt = 0; mt < 4; ++mt)
                acc[mt][nt] = __builtin_amdgcn_mfma_f32_16x16x32_bf16(af[mt], bfr, acc[mt][nt], 0, 0, 0);
        }
    }
    #pragma unroll
    for (int mt = 0; mt < 4; ++mt) {
        int ocb = ocblk * 64 + mt * 16 + q * 4;
        float4 bi = *(const float4*)(bias + ocb);
        float bia[4] = {bi.x, bi.y, bi.z, bi.w};
        #pragma unroll
        for (int nt = 0; nt < 4; ++nt) {
            int n = m0 + px0w + nt * 16 + pl;
            #pragma unroll
            for (int r = 0; r < 4; ++r) {
                int co = ocb + r;
                outK[((size_t)(b * 64 + (co >> 2))) * 65536 + (co & 3) * 16384 + n] =
                    (short)f2bs(acc[mt][nt][r] + bia[r]);
            }
        }
    }
}

// =================== Gram + squared norms ===================
__global__ __launch_bounds__(256) void gram_kernel(
        const bf16* __restrict__ Q, const bf16* __restrict__ K,
        float* __restrict__ qss, float* __restrict__ kss, float* __restrict__ gram) {
    __shared__ float Qs[64][65];
    __shared__ float Ks[64][65];
    int tid = threadIdx.x;
    int b = blockIdx.y;
    int chunk0 = blockIdx.x * 256;
    float accg[4] = {0.f, 0.f, 0.f, 0.f};
    float accq = 0.f, acck = 0.f;
    for (int t = 0; t < 4; ++t) {
        int n0 = chunk0 + t * 64;
        for (int i = 0; i < 16; ++i) {
            int idx = tid + i * 256;
            int ch = idx >> 6, px = idx & 63;
            Qs[ch][px] = b2f(Q[((size_t)b * 64 + ch) * 65536 + n0 + px]);
            Ks[ch][px] = b2f(K[((size_t)b * 64 + ch) * 65536 + n0 + px]);
        }
        __syncthreads();
        for (int px = 0; px < 64; ++px) {
            #pragma unroll
            for (int j = 0; j < 4; ++j) {
                int e = tid + j * 256;
                int rq = e >> 4;
                int rk = ((e >> 8) << 4) | (e & 15);
                accg[j] += Qs[rq & 63][px] * Ks[rk][px];
            }
            if (tid < 64) { accq += Qs[tid][px] * Qs[tid][px]; }
            else if (tid < 128) { int ch = tid - 64; acck += Ks[ch][px] * Ks[ch][px]; }
        }
        __syncthreads();
    }
    for (int j = 0; j < 4; ++j) atomicAdd(&gram[b * 1024 + tid + j * 256], accg[j]);
    if (tid < 64) atomicAdd(&qss[b * 64 + tid], accq);
    else if (tid < 128) atomicAdd(&kss[b * 64 + tid - 64], acck);
}

// =================== softmax(cos-sim * temp) ===================
__global__ void attn_kernel(const float* __restrict__ gram, const float* __restrict__ qss,
                            const float* __restrict__ kss, const float* __restrict__ temp,
                            float* __restrict__ attn) {
    int bh = blockIdx.x;
    int b = bh >> 2, h = bh & 3;
    int tid = threadIdx.x;
    __shared__ float L[16][17];
    __shared__ float rowmax[16], rowsum[16];
    int c = tid >> 4, d = tid & 15;
    float qn = fmaxf(sqrtf(qss[b * 64 + h * 16 + c]), 1e-12f);
    float kn = fmaxf(sqrtf(kss[b * 64 + h * 16 + d]), 1e-12f);
    float lg = gram[b * 1024 + h * 256 + c * 16 + d] / (qn * kn) * temp[h];
    L[c][d] = lg;
    __syncthreads();
    if (tid < 16) {
        float m = -1e30f;
        for (int j = 0; j < 16; ++j) m = fmaxf(m, L[tid][j]);
        rowmax[tid] = m;
    }
    __syncthreads();
    float e = expf(lg - rowmax[c]);
    L[c][d] = e;
    __syncthreads();
    if (tid < 16) {
        float s = 0.f;
        for (int j = 0; j < 16; ++j) s += L[tid][j];
        rowsum[tid] = s;
    }
    __syncthreads();
    attn[b * 1024 + h * 256 + c * 16 + d] = e / rowsum[c];
}

// =================== fold attn into (V -> proj) weights; A-fragment order bf16 ===================
__global__ __launch_bounds__(256) void fold_kernel(
        const float* __restrict__ attn, const float* __restrict__ w3,
        const float* __restrict__ b3, const float* __restrict__ wproj,
        short* __restrict__ WfoldF, float* __restrict__ bfold) {
    int bt = blockIdx.x;
    int b = bt >> 2, t = bt & 3;
    int tid = threadIdx.x;
    __shared__ float attn_s[1024];
    __shared__ float Aeff[64][256];
    __shared__ float beff[64];
    for (int i = 0; i < 4; ++i) attn_s[tid + i * 256] = attn[b * 1024 + tid + i * 256];
    __syncthreads();
    for (int C = 0; C < 64; ++C) {
        int h = C >> 4, c = C & 15;
        float s = 0.f;
        for (int d = 0; d < 16; ++d)
            s += attn_s[h * 256 + c * 16 + d] * w3[(size_t)(4 * (h * 16 + d) + t) * 256 + tid];
        Aeff[C][tid] = s;
    }
    if (tid < 64) {
        int h = tid >> 4, c = tid & 15;
        float s = 0.f;
        for (int d = 0; d < 16; ++d)
            s += attn_s[h * 256 + c * 16 + d] * b3[4 * (h * 16 + d) + t];
        beff[tid] = s;
    }
    __syncthreads();
    int chk = tid >> 5;
    int s5 = tid & 31;
    int j = s5 & 7;
    int laneq = (s5 >> 3) << 4;
    for (int co = 0; co < 64; ++co) {
        float wsum = 0.f;
        for (int C = 0; C < 64; ++C) wsum += wproj[co * 128 + C] * Aeff[C][tid];
        int lane2 = laneq | (co & 15);
        int mt = co >> 4;
        WfoldF[(((size_t)(bt * 8 + chk) * 4 + mt)) * 512 + lane2 * 8 + j] = (short)f2bs(wsum);
    }
    if (tid < 64) {
        float s = 0.f;
        for (int C = 0; C < 64; ++C) s += wproj[tid * 128 + C] * beff[C];
        bfold[bt * 64 + tid] = s;
    }
}

// =================== final: out = Wfold[b,t]·D1 + bfold + Wp2·I2, fp32 out ===================
__global__ __launch_bounds__(256) void final_mfma(
        const short* __restrict__ D1, const short* __restrict__ I2,
        const short* __restrict__ WfoldF, const short* __restrict__ wpF,
        const float* __restrict__ bfold, float* __restrict__ out) {
    __shared__ short inS[8192];
    int tid = threadIdx.x;
    int lane = tid & 63, wv = tid >> 6;
    int q = lane >> 4, pl = lane & 15;
    int n0 = blockIdx.x * 256;
    int b = blockIdx.y;
    int t = n0 >> 14, m0 = n0 & 16383, bt = b * 4 + t;
    int px0w = wv * 64;
    f32x4 acc[4][4];
    #pragma unroll
    for (int mt = 0; mt < 4; ++mt) {
        float4 bf4 = *(const float4*)(bfold + bt * 64 + mt * 16 + q * 4);
        #pragma unroll
        for (int nt = 0; nt < 4; ++nt)
            acc[mt][nt] = (f32x4){bf4.x, bf4.y, bf4.z, bf4.w};
    }
    for (int ch = 0; ch < 8; ++ch) {
        if (ch) __syncthreads();
        const short* src = D1 + ((size_t)(b * 16384 + m0)) * 256 + ch * 32;
        for (int tt = tid; tt < 1024; tt += 256) {
            int pix = tt >> 2, hf = tt & 3;
            *(uint4*)(inS + pix * 32 + hf * 8) = *(const uint4*)(src + (size_t)pix * 256 + hf * 8);
        }
        short8 af[4];
        #pragma unroll
        for (int mt = 0; mt < 4; ++mt)
            af[mt] = *(const short8*)(WfoldF + ((size_t)(bt * 8 + ch)) * 2048 + mt * 512 + lane * 8);
        __syncthreads();
        #pragma unroll
        for (int nt = 0; nt < 4; ++nt) {
            short8 bfr = *(const short8*)(inS + (px0w + nt * 16 + pl) * 32 + q * 8);
            #pragma unroll
            for (int mt = 0; mt < 4; ++mt)
                acc[mt][nt] = __builtin_amdgcn_mfma_f32_16x16x32_bf16(af[mt], bfr, acc[mt][nt], 0, 0, 0);
        }
    }
    for (int ch = 0; ch < 2; ++ch) {
        __syncthreads();
        const short* src = I2 + ((size_t)(b * 65536 + n0)) * 64 + ch * 32;
        for (int tt = tid; tt < 1024; tt += 256) {
            int pix = tt >> 2, hf = tt & 3;
            *(uint4*)(inS + pix * 32 + hf * 8) = *(const uint4*)(src + (size_t)pix * 64 + hf * 8);
        }
        short8 af[4];
        #pragma unroll
        for (int mt = 0; mt < 4; ++mt)
            af[mt] = *(const short8*)(wpF + (size_t)ch * 2048 + mt * 512 + lane * 8);
        __syncthreads();
        #pragma unroll
        for (int nt = 0; nt < 4; ++nt) {
            short8 bfr = *(const short8*)(inS + (px0w + nt * 16 + pl) * 32 + q * 8);
            #pragma unroll
            for (int mt = 0; mt < 4; ++mt)
                acc[mt][nt] = __builtin_amdgcn_mfma_f32_16x16x32_bf16(af[mt], bfr, acc[mt][nt], 0, 0, 0);
        }
    }
    #pragma unroll
    for (int mt = 0; mt < 4; ++mt) {
        #pragma unroll
        for (int nt = 0; nt < 4; ++nt) {
            int n = n0 + px0w + nt * 16 + pl;
            #pragma unroll
            for (int r = 0; r < 4; ++r) {
                int co = mt * 16 + q * 4 + r;
                out[((size_t)(b * 64 + co)) * 65536 + n] = acc[mt][nt][r];
            }
        }
    }
}

extern "C" void kernel_launch(void* const* d_in, const int* in_sizes, int n_in,
                              void* d_out, int out_size, void* d_ws, size_t ws_size,
                              hipStream_t stream) {
    const float* x     = (const float*)d_in[0];
    const float* temp  = (const float*)d_in[1];
    const float* w1    = (const float*)d_in[2];
    const float* b1    = (const float*)d_in[3];
    const float* w2    = (const float*)d_in[4];
    const float* b2    = (const float*)d_in[5];
    const float* w3    = (const float*)d_in[6];
    const float* b3    = (const float*)d_in[7];
    const float* wdwt  = (const float*)d_in[8];
    const float* bdwt  = (const float*)d_in[9];
    const float* widwt = (const float*)d_in[10];
    const float* bidwt = (const float*)d_in[11];
    const float* wproj = (const float*)d_in[12];
    float* out = (float*)d_out;

    char* W8 = (char*)d_ws;
    const size_t SLOT = 16777216;
    short* slotA = (short*)(W8);              // D0cl -> I0cl -> Qb
    short* slotB = (short*)(W8 + SLOT);       // D1cl
    short* slotC = (short*)(W8 + 2 * SLOT);   // I2cl
    short* slotD = (short*)(W8 + 3 * SLOT);   // Kb
    char* P = W8 + 4 * SLOT;
    short* wF1    = (short*)P; P += 2 * 655360;
    short* wF2c   = (short*)P; P += 2 * 40960;
    short* wFk    = (short*)P; P += 2 * 65536;
    short* wpF    = (short*)P; P += 2 * 4096;
    short* wFq    = (short*)P; P += 2 * 4096;
    short* WfoldF = (short*)P; P += 2 * 131072;
    float* scr    = (float*)P;
    float* qss   = scr;
    float* kss   = scr + 128;
    float* gram  = scr + 256;
    float* attn  = scr + 2304;
    float* bfold = scr + 4352;

    prep_all<<<3009, 256, 0, stream>>>(wdwt, widwt, w2, wproj, w1,
                                       wF1, wF2c, wFk, wpF, wFq, scr);

    // DWT branch
    dwt_kernel<<<dim3(2, 128, 2), 256, 0, stream>>>(x, slotA);
    conv3_v2<256, 64, 1><<<dim3(2, 128, 2), 256, 12672, stream>>>(slotA, wF1, bdwt, slotB, 128, 128);

    // IDWT branch
    idwt_kernel<<<8192, 256, 0, stream>>>(slotB, slotA);
    conv3_v2<64, 256, 4><<<dim3(1, 256, 2), 256, 49536, stream>>>(slotA, wF2c, bidwt, slotC, 256, 256);

    // Q (MFMA from fp32 x) and K (MFMA)
    qconv_mfma<<<dim3(256, 2), 256, 0, stream>>>(x, wFq, b1, slotA);
    kconv_mfma<<<dim3(4, 64, 2), 256, 0, stream>>>(slotB, wFk, b2, slotD);

    // attention stats -> softmax -> fold
    gram_kernel<<<dim3(256, 2), 256, 0, stream>>>((bf16*)slotA, (bf16*)slotD, qss, kss, gram);
    attn_kernel<<<8, 256, 0, stream>>>(gram, qss, kss, temp, attn);
    fold_kernel<<<8, 256, 0, stream>>>(attn, w3, b3, wproj, WfoldF, bfold);

    // fused (attn·V + proj) + idwt-branch proj
    final_mfma<<<dim3(256, 2), 256, 0, stream>>>(slotB, slotC, WfoldF, wpF, bfold, out);
}

// Round 5
// 345.719 us; speedup vs baseline: 3.2421x; 1.1727x over previous
//
#include <hip/hip_runtime.h>
#include <hip/hip_bf16.h>

typedef __hip_bfloat16 bf16;
typedef __attribute__((ext_vector_type(8))) short short8;
typedef __attribute__((ext_vector_type(4))) float f32x4;
typedef unsigned short u16;
typedef unsigned int u32;

static __device__ __forceinline__ float b2f(bf16 v) { return __bfloat162float(v); }
static __device__ __forceinline__ u16 f2bs(float f) {
    bf16 h = __float2bfloat16(f);
    return *reinterpret_cast<u16*>(&h);
}
static __device__ __forceinline__ float bs2f(u16 u) {
    union { float f; u32 i; } x; x.i = ((u32)u) << 16; return x.f;
}
static __device__ __forceinline__ uint4 pack8(const u16* p) {
    uint4 v;
    v.x = (u32)p[0] | ((u32)p[1] << 16);
    v.y = (u32)p[2] | ((u32)p[3] << 16);
    v.z = (u32)p[4] | ((u32)p[5] << 16);
    v.w = (u32)p[6] | ((u32)p[7] << 16);
    return v;
}

// =================== merged weight prep ===================
__device__ __forceinline__ void prep3_body(const float* __restrict__ w, short* __restrict__ wF,
                                           int C, int idx) {
    int j = idx & 7;
    int lane = (idx >> 3) & 63;
    int mt = (idx >> 9) & 3;
    int rest = idx >> 11;
    int pair = rest % 5;
    int bo = rest / 5;
    int nchunks = C / 16;
    int ch = bo % nchunks;
    int ocblk = bo / nchunks;
    int s = ((lane >> 4) * 8 + j);
    int tp = 2 * pair + (s >> 4);
    int ci = ch * 16 + (s & 15);
    int oc = ocblk * 64 + mt * 16 + (lane & 15);
    float v = (tp <= 8) ? w[((size_t)(oc * C + ci)) * 9 + tp] : 0.f;
    wF[idx] = (short)f2bs(v);
}
__device__ __forceinline__ void prep1_body(const float* __restrict__ w, short* __restrict__ wF,
                                           int Cin, int cioff, int nchunks, int idx) {
    int j = idx & 7;
    int lane = (idx >> 3) & 63;
    int mt = (idx >> 9) & 3;
    int bo = idx >> 11;
    int ch = bo % nchunks;
    int ocblk = bo / nchunks;
    int s = (lane >> 4) * 8 + j;
    int ci = cioff + ch * 32 + s;
    int oc = ocblk * 64 + mt * 16 + (lane & 15);
    wF[idx] = (short)f2bs(w[(size_t)oc * Cin + ci]);
}

__global__ __launch_bounds__(256) void prep_all(
        const float* __restrict__ wdwt, const float* __restrict__ widwt,
        const float* __restrict__ w2, const float* __restrict__ wproj,
        const float* __restrict__ w1,
        short* __restrict__ wF1, short* __restrict__ wF2c, short* __restrict__ wFk,
        short* __restrict__ wpF, short* __restrict__ wFq, float* __restrict__ scr) {
    int blk = blockIdx.x;
    int tid = threadIdx.x;
    if (blk < 2560) {
        prep3_body(wdwt, wF1, 256, blk * 256 + tid);
    } else if (blk < 2720) {
        prep3_body(widwt, wF2c, 64, (blk - 2560) * 256 + tid);
    } else if (blk < 2976) {
        prep1_body(w2, wFk, 256, 0, 8, (blk - 2720) * 256 + tid);
    } else if (blk < 2992) {
        prep1_body(wproj, wpF, 128, 64, 2, (blk - 2976) * 256 + tid);
    } else if (blk < 3008) {
        prep1_body(w1, wFq, 64, 0, 2, (blk - 2992) * 256 + tid);
    } else {
        for (int i = tid; i < 4864; i += 256) scr[i] = 0.f;
    }
}

// =================== Haar DWT ===================
__global__ __launch_bounds__(256) void dwt_kernel(const float* __restrict__ x, short* __restrict__ d0) {
    __shared__ u16 Xs[32][2][256];
    int cc = blockIdx.x;
    int y = blockIdx.y;
    int b = blockIdx.z;
    int tid = threadIdx.x;
    int c = tid >> 3;
    int xo = tid & 7;
    const float* xb = x + ((size_t)((b * 64 + cc * 32 + c) * 256 + 2 * y)) * 256;
    for (int r = 0; r < 2; ++r) {
        const float* row = xb + r * 256;
        #pragma unroll
        for (int k = 0; k < 8; ++k) {
            int xx = xo * 32 + k * 4;
            float4 v = *(const float4*)(row + xx);
            uint2 pk;
            pk.x = (u32)f2bs(v.x) | ((u32)f2bs(v.y) << 16);
            pk.y = (u32)f2bs(v.z) | ((u32)f2bs(v.w) << 16);
            *(uint2*)&Xs[c][r][xx] = pk;
        }
    }
    __syncthreads();
    int px = tid >> 1;
    int half = tid & 1;
    u16 obuf[4][16];
    #pragma unroll
    for (int ci = 0; ci < 16; ++ci) {
        int cl = half * 16 + ci;
        float a = bs2f(Xs[cl][0][2 * px]);
        float bb = bs2f(Xs[cl][0][2 * px + 1]);
        float c2 = bs2f(Xs[cl][1][2 * px]);
        float dd = bs2f(Xs[cl][1][2 * px + 1]);
        obuf[0][ci] = f2bs((a - bb + c2 - dd) * 0.5f);  // lh
        obuf[1][ci] = f2bs((a + bb - c2 - dd) * 0.5f);  // hl
        obuf[2][ci] = f2bs((a - bb - c2 + dd) * 0.5f);  // hh
        obuf[3][ci] = f2bs((a + bb + c2 + dd) * 0.5f);  // ll
    }
    size_t P = ((size_t)(b * 128 + y) * 128 + px) * 256;
    for (int g = 0; g < 4; ++g) {
        *(uint4*)&d0[P + g * 64 + cc * 32 + half * 16] = pack8(&obuf[g][0]);
        *(uint4*)&d0[P + g * 64 + cc * 32 + half * 16 + 8] = pack8(&obuf[g][8]);
    }
}

// =================== Haar IDWT ===================
__global__ __launch_bounds__(256) void idwt_kernel(const short* __restrict__ d1, short* __restrict__ i0) {
    int tid = threadIdx.x;
    int lane = tid & 63;
    int p = blockIdx.x * 4 + (tid >> 6);
    int b = p >> 14, m = p & 16383;
    ushort4 v = *(const ushort4*)(d1 + ((size_t)(b * 16384 + m)) * 256 + 4 * lane);
    float yl = bs2f(v.x), lh = bs2f(v.y), hl = bs2f(v.z), hh = bs2f(v.w);
    float a_ = (yl + lh + hl + hh) * 0.5f;
    float b_ = (yl - lh + hl - hh) * 0.5f;
    float c_ = (yl + lh - hl - hh) * 0.5f;
    float d_ = (yl - lh - hl + hh) * 0.5f;
    int y = m >> 7, xx = m & 127;
    u16* o = (u16*)i0;
    size_t base = ((size_t)(b * 256 + 2 * y) * 256 + 2 * xx) * 64 + lane;
    o[base] = f2bs(a_);
    o[base + 64] = f2bs(b_);
    o[base + 256 * 64] = f2bs(c_);
    o[base + 256 * 64 + 64] = f2bs(d_);
}

// =================== 3x3 conv v2 (pipelined, input-only LDS, global A-frags) ===================
template <int C, int NPX, int WPG>
__global__ __launch_bounds__(256) void conv3_v2(
        const short* __restrict__ in, const short* __restrict__ wF,
        const float* __restrict__ bias, short* __restrict__ out,
        int H, int W) {
    constexpr int Wp = NPX + 2;
    constexpr int NCH = C / 16;
    constexpr int UNITS = 3 * Wp * 2;
    constexpr int UPT = (UNITS + 255) / 256;
    constexpr int BUFSZ = 3 * Wp * 16;
    extern __shared__ __align__(16) short inS[];

    int tid = threadIdx.x;
    int lane = tid & 63, wv = tid >> 6;
    int q = lane >> 4, pl = lane & 15;
    int ocg = wv / WPG;
    int pxoff = (wv % WPG) * 64;
    int x0 = blockIdx.x * NPX;
    int y = blockIdx.y;
    int b = blockIdx.z;

    int gbase[UPT];
    int ldsoff[UPT];
    #pragma unroll
    for (int k2 = 0; k2 < UPT; ++k2) {
        int u = k2 * 256 + tid;
        if (u < UNITS) {
            int r = u / (Wp * 2);
            int rem = u - r * (Wp * 2);
            int px = rem >> 1, hf = rem & 1;
            int ry = y - 1 + r;
            if (ry < 0) ry = 1;
            if (ry >= H) ry = H - 2;
            int rx = x0 - 1 + px;
            if (rx < 0) rx = 1;
            if (rx >= W) rx = W - 2;
            gbase[k2] = ((b * H + ry) * W + rx) * C + hf * 8;
            ldsoff[k2] = (r * Wp + px) * 16 + hf * 8;
        } else { gbase[k2] = 0; ldsoff[k2] = -1; }
    }

    f32x4 acc[4][4];
    #pragma unroll
    for (int mt = 0; mt < 4; ++mt)
        #pragma unroll
        for (int nt = 0; nt < 4; ++nt)
            acc[mt][nt] = (f32x4){0.f, 0.f, 0.f, 0.f};

    uint4 pf[UPT];
    #pragma unroll
    for (int k2 = 0; k2 < UPT; ++k2)
        if (ldsoff[k2] >= 0) pf[k2] = *(const uint4*)(in + gbase[k2]);
    #pragma unroll
    for (int k2 = 0; k2 < UPT; ++k2)
        if (ldsoff[k2] >= 0) *(uint4*)(inS + ldsoff[k2]) = pf[k2];
    __syncthreads();

    #pragma unroll 1
    for (int ch = 0; ch < NCH; ++ch) {
        const short* buf = inS + (ch & 1) * BUFSZ;
        short* nbuf = inS + ((ch + 1) & 1) * BUFSZ;
        bool more = (ch + 1 < NCH);
        if (more) {
            #pragma unroll
            for (int k2 = 0; k2 < UPT; ++k2)
                if (ldsoff[k2] >= 0) pf[k2] = *(const uint4*)(in + gbase[k2] + (ch + 1) * 16);
        }
        const short* wbase = wF + ((size_t)(ocg * NCH + ch) * 5) * 2048;
        short8 afA[4], afB[4];
        #pragma unroll
        for (int mt = 0; mt < 4; ++mt)
            afA[mt] = *(const short8*)(wbase + mt * 512 + lane * 8);
        #pragma unroll
        for (int pr = 0; pr < 5; ++pr) {
            const short8* afc = (pr & 1) ? afB : afA;
            short8* afn = (pr & 1) ? afA : afB;
            if (pr < 4) {
                #pragma unroll
                for (int mt = 0; mt < 4; ++mt)
                    afn[mt] = *(const short8*)(wbase + ((pr + 1) * 4 + mt) * 512 + lane * 8);
            }
            int t1 = 2 * pr + (q >> 1);
            if (t1 > 8) t1 = 8;
            int ti = (t1 >= 6) ? 2 : ((t1 >= 3) ? 1 : 0);
            int tj = t1 - ti * 3;
            #pragma unroll
            for (int nt = 0; nt < 4; ++nt) {
                int i = pxoff + nt * 16 + pl + tj;
                short8 bfr = *(const short8*)(buf + (ti * Wp + i) * 16 + (q & 1) * 8);
                #pragma unroll
                for (int mt = 0; mt < 4; ++mt)
                    acc[mt][nt] = __builtin_amdgcn_mfma_f32_16x16x32_bf16(afc[mt], bfr, acc[mt][nt], 0, 0, 0);
            }
        }
        if (more) {
            #pragma unroll
            for (int k2 = 0; k2 < UPT; ++k2)
                if (ldsoff[k2] >= 0) *(uint4*)(nbuf + ldsoff[k2]) = pf[k2];
            __syncthreads();
        }
    }

    #pragma unroll
    for (int mt = 0; mt < 4; ++mt) {
        int ocb = ocg * 64 + mt * 16 + q * 4;
        float4 bi = *(const float4*)(bias + ocb);
        float bia[4] = {bi.x, bi.y, bi.z, bi.w};
        #pragma unroll
        for (int nt = 0; nt < 4; ++nt) {
            int xl = x0 + pxoff + nt * 16 + pl;
            ushort4 pk;
            float v0 = acc[mt][nt][0] + bia[0]; pk.x = f2bs(v0 >= 0.f ? v0 : 0.01f * v0);
            float v1 = acc[mt][nt][1] + bia[1]; pk.y = f2bs(v1 >= 0.f ? v1 : 0.01f * v1);
            float v2 = acc[mt][nt][2] + bia[2]; pk.z = f2bs(v2 >= 0.f ? v2 : 0.01f * v2);
            float v3 = acc[mt][nt][3] + bia[3]; pk.w = f2bs(v3 >= 0.f ? v3 : 0.01f * v3);
            *(ushort4*)(out + (((size_t)(b * H + y)) * W + xl) * C + ocb) = pk;
        }
    }
}

// =================== Q conv 1x1 MFMA ===================
__global__ __launch_bounds__(256) void qconv_mfma(
        const float* __restrict__ x, const short* __restrict__ wFq,
        const float* __restrict__ bias, short* __restrict__ outQ) {
    __shared__ short inS[256 * 32];
    int tid = threadIdx.x;
    int lane = tid & 63, wv = tid >> 6;
    int q = lane >> 4, pl = lane & 15;
    int n0 = blockIdx.x * 256;
    int b = blockIdx.y;
    int pxoff = wv * 64;
    f32x4 acc[4][4];
    #pragma unroll
    for (int mt = 0; mt < 4; ++mt)
        #pragma unroll
        for (int nt = 0; nt < 4; ++nt)
            acc[mt][nt] = (f32x4){0.f, 0.f, 0.f, 0.f};

    for (int ch = 0; ch < 2; ++ch) {
        if (ch) __syncthreads();
        #pragma unroll
        for (int k2 = 0; k2 < 8; ++k2) {
            int u = k2 * 256 + tid;
            int cc = u >> 6;
            int p4 = (u & 63) * 4;
            float4 v = *(const float4*)(x + ((size_t)(b * 64 + ch * 32 + cc)) * 65536 + n0 + p4);
            inS[(p4 + 0) * 32 + cc] = (short)f2bs(v.x);
            inS[(p4 + 1) * 32 + cc] = (short)f2bs(v.y);
            inS[(p4 + 2) * 32 + cc] = (short)f2bs(v.z);
            inS[(p4 + 3) * 32 + cc] = (short)f2bs(v.w);
        }
        short8 af[4];
        #pragma unroll
        for (int mt = 0; mt < 4; ++mt)
            af[mt] = *(const short8*)(wFq + (ch * 4 + mt) * 512 + lane * 8);
        __syncthreads();
        #pragma unroll
        for (int nt = 0; nt < 4; ++nt) {
            short8 bfr = *(const short8*)(inS + (pxoff + nt * 16 + pl) * 32 + q * 8);
            #pragma unroll
            for (int mt = 0; mt < 4; ++mt)
                acc[mt][nt] = __builtin_amdgcn_mfma_f32_16x16x32_bf16(af[mt], bfr, acc[mt][nt], 0, 0, 0);
        }
    }
    #pragma unroll
    for (int mt = 0; mt < 4; ++mt) {
        int ocb = mt * 16 + q * 4;
        float4 bi = *(const float4*)(bias + ocb);
        float bia[4] = {bi.x, bi.y, bi.z, bi.w};
        #pragma unroll
        for (int nt = 0; nt < 4; ++nt) {
            int n = n0 + pxoff + nt * 16 + pl;
            #pragma unroll
            for (int r = 0; r < 4; ++r)
                outQ[((size_t)(b * 64 + ocb + r)) * 65536 + n] = (short)f2bs(acc[mt][nt][r] + bia[r]);
        }
    }
}

// =================== K conv 1x1 MFMA ===================
__global__ __launch_bounds__(256) void kconv_mfma(
        const short* __restrict__ in, const short* __restrict__ wF,
        const float* __restrict__ bias, short* __restrict__ outK) {
    __shared__ short inS[8192];
    int tid = threadIdx.x;
    int lane = tid & 63, wv = tid >> 6;
    int q = lane >> 4, pl = lane & 15;
    int ocblk = blockIdx.x;
    int m0 = blockIdx.y * 256;
    int b = blockIdx.z;
    int px0w = wv * 64;
    f32x4 acc[4][4];
    #pragma unroll
    for (int mt = 0; mt < 4; ++mt)
        #pragma unroll
        for (int nt = 0; nt < 4; ++nt)
            acc[mt][nt] = (f32x4){0.f, 0.f, 0.f, 0.f};

    for (int ch = 0; ch < 8; ++ch) {
        if (ch) __syncthreads();
        const short* src = in + ((size_t)(b * 16384 + m0)) * 256 + ch * 32;
        for (int t = tid; t < 1024; t += 256) {
            int pix = t >> 2, hf = t & 3;
            *(uint4*)(inS + pix * 32 + hf * 8) = *(const uint4*)(src + (size_t)pix * 256 + hf * 8);
        }
        short8 af[4];
        #pragma unroll
        for (int mt = 0; mt < 4; ++mt)
            af[mt] = *(const short8*)(wF + ((size_t)(ocblk * 8 + ch)) * 2048 + mt * 512 + lane * 8);
        __syncthreads();
        #pragma unroll
        for (int nt = 0; nt < 4; ++nt) {
            short8 bfr = *(const short8*)(inS + (px0w + nt * 16 + pl) * 32 + q * 8);
            #pragma unroll
            for (int mt = 0; mt < 4; ++mt)
                acc[mt][nt] = __builtin_amdgcn_mfma_f32_16x16x32_bf16(af[mt], bfr, acc[mt][nt], 0, 0, 0);
        }
    }
    #pragma unroll
    for (int mt = 0; mt < 4; ++mt) {
        int ocb = ocblk * 64 + mt * 16 + q * 4;
        float4 bi = *(const float4*)(bias + ocb);
        float bia[4] = {bi.x, bi.y, bi.z, bi.w};
        #pragma unroll
        for (int nt = 0; nt < 4; ++nt) {
            int n = m0 + px0w + nt * 16 + pl;
            #pragma unroll
            for (int r = 0; r < 4; ++r) {
                int co = ocb + r;
                outK[((size_t)(b * 64 + (co >> 2))) * 65536 + (co & 3) * 16384 + n] =
                    (short)f2bs(acc[mt][nt][r] + bia[r]);
            }
        }
    }
}

// =================== Gram + squared norms ===================
__global__ __launch_bounds__(256) void gram_kernel(
        const bf16* __restrict__ Q, const bf16* __restrict__ K,
        float* __restrict__ qss, float* __restrict__ kss, float* __restrict__ gram) {
    __shared__ float Qs[64][65];
    __shared__ float Ks[64][65];
    int tid = threadIdx.x;
    int b = blockIdx.y;
    int chunk0 = blockIdx.x * 256;
    float accg[4] = {0.f, 0.f, 0.f, 0.f};
    float accq = 0.f, acck = 0.f;
    for (int t = 0; t < 4; ++t) {
        int n0 = chunk0 + t * 64;
        for (int i = 0; i < 16; ++i) {
            int idx = tid + i * 256;
            int ch = idx >> 6, px = idx & 63;
            Qs[ch][px] = b2f(Q[((size_t)b * 64 + ch) * 65536 + n0 + px]);
            Ks[ch][px] = b2f(K[((size_t)b * 64 + ch) * 65536 + n0 + px]);
        }
        __syncthreads();
        for (int px = 0; px < 64; ++px) {
            #pragma unroll
            for (int j = 0; j < 4; ++j) {
                int e = tid + j * 256;
                int rq = e >> 4;
                int rk = ((e >> 8) << 4) | (e & 15);
                accg[j] += Qs[rq & 63][px] * Ks[rk][px];
            }
            if (tid < 64) { accq += Qs[tid][px] * Qs[tid][px]; }
            else if (tid < 128) { int ch = tid - 64; acck += Ks[ch][px] * Ks[ch][px]; }
        }
        __syncthreads();
    }
    for (int j = 0; j < 4; ++j) atomicAdd(&gram[b * 1024 + tid + j * 256], accg[j]);
    if (tid < 64) atomicAdd(&qss[b * 64 + tid], accq);
    else if (tid < 128) atomicAdd(&kss[b * 64 + tid - 64], acck);
}

// =================== softmax(cos-sim * temp) ===================
__global__ void attn_kernel(const float* __restrict__ gram, const float* __restrict__ qss,
                            const float* __restrict__ kss, const float* __restrict__ temp,
                            float* __restrict__ attn) {
    int bh = blockIdx.x;
    int b = bh >> 2, h = bh & 3;
    int tid = threadIdx.x;
    __shared__ float L[16][17];
    __shared__ float rowmax[16], rowsum[16];
    int c = tid >> 4, d = tid & 15;
    float qn = fmaxf(sqrtf(qss[b * 64 + h * 16 + c]), 1e-12f);
    float kn = fmaxf(sqrtf(kss[b * 64 + h * 16 + d]), 1e-12f);
    float lg = gram[b * 1024 + h * 256 + c * 16 + d] / (qn * kn) * temp[h];
    L[c][d] = lg;
    __syncthreads();
    if (tid < 16) {
        float m = -1e30f;
        for (int j = 0; j < 16; ++j) m = fmaxf(m, L[tid][j]);
        rowmax[tid] = m;
    }
    __syncthreads();
    float e = expf(lg - rowmax[c]);
    L[c][d] = e;
    __syncthreads();
    if (tid < 16) {
        float s = 0.f;
        for (int j = 0; j < 16; ++j) s += L[tid][j];
        rowsum[tid] = s;
    }
    __syncthreads();
    attn[b * 1024 + h * 256 + c * 16 + d] = e / rowsum[c];
}

// =================== fold v2: 128 blocks, LDS-resident, A-frag output ===================
// grid (16 ci-chunks, 8 bt). Stage1: Aeff[64][16] per ci strip; Stage2: Wp1·Aeff.
__global__ __launch_bounds__(256) void fold_v2(
        const float* __restrict__ attn, const float* __restrict__ w3,
        const float* __restrict__ b3, const float* __restrict__ wproj,
        short* __restrict__ WfoldF, float* __restrict__ bfold) {
    __shared__ float attn_s[1024];
    __shared__ float wp_s[64][65];
    __shared__ float Aeff_s[64][17];
    __shared__ float beff[64];
    int bt = blockIdx.y;
    int b = bt >> 2, t = bt & 3;
    int ci0 = blockIdx.x * 16;
    int tid = threadIdx.x;
    for (int i = 0; i < 4; ++i) attn_s[tid + i * 256] = attn[b * 1024 + tid + i * 256];
    #pragma unroll
    for (int i = 0; i < 16; ++i) {
        int idx = tid + i * 256;
        int co = idx >> 6, C = idx & 63;
        wp_s[co][C] = wproj[co * 128 + C];
    }
    __syncthreads();
    // stage 1: Aeff[C][ci_l] = sum_d attn[h,c,d] * w3[4*(h*16+d)+t][ci0+ci_l]
    #pragma unroll
    for (int pass = 0; pass < 4; ++pass) {
        int el = pass * 256 + tid;
        int C = el >> 4, ci_l = el & 15;
        int h = C >> 4, c = C & 15;
        float s = 0.f;
        #pragma unroll
        for (int d = 0; d < 16; ++d)
            s += attn_s[h * 256 + c * 16 + d] * w3[(size_t)(4 * (h * 16 + d) + t) * 256 + ci0 + ci_l];
        Aeff_s[C][ci_l] = s;
    }
    if (blockIdx.x == 0 && tid < 64) {
        int h = tid >> 4, c = tid & 15;
        float s = 0.f;
        #pragma unroll
        for (int d = 0; d < 16; ++d)
            s += attn_s[h * 256 + c * 16 + d] * b3[4 * (h * 16 + d) + t];
        beff[tid] = s;
    }
    __syncthreads();
    // stage 2: Wfold[ci][co] = sum_C wp_s[co][C] * Aeff_s[C][ci_l]
    #pragma unroll
    for (int pass = 0; pass < 4; ++pass) {
        int el = pass * 256 + tid;
        int ci_l = el >> 6, co = el & 63;
        float s = 0.f;
        #pragma unroll
        for (int C = 0; C < 64; ++C) s += wp_s[co][C] * Aeff_s[C][ci_l];
        int ci = ci0 + ci_l;
        int chk = ci >> 5;
        int s5 = ci & 31;
        int j = s5 & 7;
        int lane2 = (((s5 >> 3) << 4)) | (co & 15);
        int mt = co >> 4;
        WfoldF[(((size_t)(bt * 8 + chk) * 4 + mt)) * 512 + lane2 * 8 + j] = (short)f2bs(s);
    }
    if (blockIdx.x == 0 && tid < 64) {
        float s = 0.f;
        #pragma unroll
        for (int C = 0; C < 64; ++C) s += wp_s[tid][C] * beff[C];
        bfold[bt * 64 + tid] = s;
    }
}

// =================== final: out = Wfold[b,t]·D1 + bfold + Wp2·I2, fp32 out ===================
__global__ __launch_bounds__(256) void final_mfma(
        const short* __restrict__ D1, const short* __restrict__ I2,
        const short* __restrict__ WfoldF, const short* __restrict__ wpF,
        const float* __restrict__ bfold, float* __restrict__ out) {
    __shared__ short inS[8192];
    int tid = threadIdx.x;
    int lane = tid & 63, wv = tid >> 6;
    int q = lane >> 4, pl = lane & 15;
    int n0 = blockIdx.x * 256;
    int b = blockIdx.y;
    int t = n0 >> 14, m0 = n0 & 16383, bt = b * 4 + t;
    int px0w = wv * 64;
    f32x4 acc[4][4];
    #pragma unroll
    for (int mt = 0; mt < 4; ++mt) {
        float4 bf4 = *(const float4*)(bfold + bt * 64 + mt * 16 + q * 4);
        #pragma unroll
        for (int nt = 0; nt < 4; ++nt)
            acc[mt][nt] = (f32x4){bf4.x, bf4.y, bf4.z, bf4.w};
    }
    for (int ch = 0; ch < 8; ++ch) {
        if (ch) __syncthreads();
        const short* src = D1 + ((size_t)(b * 16384 + m0)) * 256 + ch * 32;
        for (int tt = tid; tt < 1024; tt += 256) {
            int pix = tt >> 2, hf = tt & 3;
            *(uint4*)(inS + pix * 32 + hf * 8) = *(const uint4*)(src + (size_t)pix * 256 + hf * 8);
        }
        short8 af[4];
        #pragma unroll
        for (int mt = 0; mt < 4; ++mt)
            af[mt] = *(const short8*)(WfoldF + ((size_t)(bt * 8 + ch)) * 2048 + mt * 512 + lane * 8);
        __syncthreads();
        #pragma unroll
        for (int nt = 0; nt < 4; ++nt) {
            short8 bfr = *(const short8*)(inS + (px0w + nt * 16 + pl) * 32 + q * 8);
            #pragma unroll
            for (int mt = 0; mt < 4; ++mt)
                acc[mt][nt] = __builtin_amdgcn_mfma_f32_16x16x32_bf16(af[mt], bfr, acc[mt][nt], 0, 0, 0);
        }
    }
    for (int ch = 0; ch < 2; ++ch) {
        __syncthreads();
        const short* src = I2 + ((size_t)(b * 65536 + n0)) * 64 + ch * 32;
        for (int tt = tid; tt < 1024; tt += 256) {
            int pix = tt >> 2, hf = tt & 3;
            *(uint4*)(inS + pix * 32 + hf * 8) = *(const uint4*)(src + (size_t)pix * 64 + hf * 8);
        }
        short8 af[4];
        #pragma unroll
        for (int mt = 0; mt < 4; ++mt)
            af[mt] = *(const short8*)(wpF + (size_t)ch * 2048 + mt * 512 + lane * 8);
        __syncthreads();
        #pragma unroll
        for (int nt = 0; nt < 4; ++nt) {
            short8 bfr = *(const short8*)(inS + (px0w + nt * 16 + pl) * 32 + q * 8);
            #pragma unroll
            for (int mt = 0; mt < 4; ++mt)
                acc[mt][nt] = __builtin_amdgcn_mfma_f32_16x16x32_bf16(af[mt], bfr, acc[mt][nt], 0, 0, 0);
        }
    }
    #pragma unroll
    for (int mt = 0; mt < 4; ++mt) {
        #pragma unroll
        for (int nt = 0; nt < 4; ++nt) {
            int n = n0 + px0w + nt * 16 + pl;
            #pragma unroll
            for (int r = 0; r < 4; ++r) {
                int co = mt * 16 + q * 4 + r;
                out[((size_t)(b * 64 + co)) * 65536 + n] = acc[mt][nt][r];
            }
        }
    }
}

extern "C" void kernel_launch(void* const* d_in, const int* in_sizes, int n_in,
                              void* d_out, int out_size, void* d_ws, size_t ws_size,
                              hipStream_t stream) {
    const float* x     = (const float*)d_in[0];
    const float* temp  = (const float*)d_in[1];
    const float* w1    = (const float*)d_in[2];
    const float* b1    = (const float*)d_in[3];
    const float* w2    = (const float*)d_in[4];
    const float* b2    = (const float*)d_in[5];
    const float* w3    = (const float*)d_in[6];
    const float* b3    = (const float*)d_in[7];
    const float* wdwt  = (const float*)d_in[8];
    const float* bdwt  = (const float*)d_in[9];
    const float* widwt = (const float*)d_in[10];
    const float* bidwt = (const float*)d_in[11];
    const float* wproj = (const float*)d_in[12];
    float* out = (float*)d_out;

    char* W8 = (char*)d_ws;
    const size_t SLOT = 16777216;
    short* slotA = (short*)(W8);              // D0cl -> I0cl -> Qb
    short* slotB = (short*)(W8 + SLOT);       // D1cl
    short* slotC = (short*)(W8 + 2 * SLOT);   // I2cl
    short* slotD = (short*)(W8 + 3 * SLOT);   // Kb
    char* P = W8 + 4 * SLOT;
    short* wF1    = (short*)P; P += 2 * 655360;
    short* wF2c   = (short*)P; P += 2 * 40960;
    short* wFk    = (short*)P; P += 2 * 65536;
    short* wpF    = (short*)P; P += 2 * 4096;
    short* wFq    = (short*)P; P += 2 * 4096;
    short* WfoldF = (short*)P; P += 2 * 131072;
    float* scr    = (float*)P;
    float* qss   = scr;
    float* kss   = scr + 128;
    float* gram  = scr + 256;
    float* attn  = scr + 2304;
    float* bfold = scr + 4352;

    prep_all<<<3009, 256, 0, stream>>>(wdwt, widwt, w2, wproj, w1,
                                       wF1, wF2c, wFk, wpF, wFq, scr);

    // DWT branch
    dwt_kernel<<<dim3(2, 128, 2), 256, 0, stream>>>(x, slotA);
    conv3_v2<256, 64, 1><<<dim3(2, 128, 2), 256, 12672, stream>>>(slotA, wF1, bdwt, slotB, 128, 128);

    // IDWT branch
    idwt_kernel<<<8192, 256, 0, stream>>>(slotB, slotA);
    conv3_v2<64, 256, 4><<<dim3(1, 256, 2), 256, 49536, stream>>>(slotA, wF2c, bidwt, slotC, 256, 256);

    // Q (MFMA from fp32 x) and K (MFMA)
    qconv_mfma<<<dim3(256, 2), 256, 0, stream>>>(x, wFq, b1, slotA);
    kconv_mfma<<<dim3(4, 64, 2), 256, 0, stream>>>(slotB, wFk, b2, slotD);

    // attention stats -> softmax -> fold
    gram_kernel<<<dim3(256, 2), 256, 0, stream>>>((bf16*)slotA, (bf16*)slotD, qss, kss, gram);
    attn_kernel<<<8, 256, 0, stream>>>(gram, qss, kss, temp, attn);
    fold_v2<<<dim3(16, 8), 256, 0, stream>>>(attn, w3, b3, wproj, WfoldF, bfold);

    // fused (attn·V + proj) + idwt-branch proj
    final_mfma<<<dim3(256, 2), 256, 0, stream>>>(slotB, slotC, WfoldF, wpF, bfold, out);
}

// Round 6
// 298.221 us; speedup vs baseline: 3.7585x; 1.1593x over previous
//
#include <hip/hip_runtime.h>
#include <hip/hip_bf16.h>

typedef __hip_bfloat16 bf16;
typedef __attribute__((ext_vector_type(8))) short short8;
typedef __attribute__((ext_vector_type(4))) float f32x4;
typedef unsigned short u16;
typedef unsigned int u32;

static __device__ __forceinline__ u16 f2bs(float f) {
    bf16 h = __float2bfloat16(f);
    return *reinterpret_cast<u16*>(&h);
}
static __device__ __forceinline__ float bs2f(u16 u) {
    union { float f; u32 i; } x; x.i = ((u32)u) << 16; return x.f;
}
static __device__ __forceinline__ uint4 pack8(const u16* p) {
    uint4 v;
    v.x = (u32)p[0] | ((u32)p[1] << 16);
    v.y = (u32)p[2] | ((u32)p[3] << 16);
    v.z = (u32)p[4] | ((u32)p[5] << 16);
    v.w = (u32)p[6] | ((u32)p[7] << 16);
    return v;
}

// =================== merged weight prep ===================
__device__ __forceinline__ void prep3_body(const float* __restrict__ w, short* __restrict__ wF,
                                           int C, int idx) {
    int j = idx & 7;
    int lane = (idx >> 3) & 63;
    int mt = (idx >> 9) & 3;
    int rest = idx >> 11;
    int pair = rest % 5;
    int bo = rest / 5;
    int nchunks = C / 16;
    int ch = bo % nchunks;
    int ocblk = bo / nchunks;
    int s = ((lane >> 4) * 8 + j);
    int tp = 2 * pair + (s >> 4);
    int ci = ch * 16 + (s & 15);
    int oc = ocblk * 64 + mt * 16 + (lane & 15);
    float v = (tp <= 8) ? w[((size_t)(oc * C + ci)) * 9 + tp] : 0.f;
    wF[idx] = (short)f2bs(v);
}
__device__ __forceinline__ void prep1_body(const float* __restrict__ w, short* __restrict__ wF,
                                           int Cin, int cioff, int nchunks, int idx) {
    int j = idx & 7;
    int lane = (idx >> 3) & 63;
    int mt = (idx >> 9) & 3;
    int bo = idx >> 11;
    int ch = bo % nchunks;
    int ocblk = bo / nchunks;
    int s = (lane >> 4) * 8 + j;
    int ci = cioff + ch * 32 + s;
    int oc = ocblk * 64 + mt * 16 + (lane & 15);
    wF[idx] = (short)f2bs(w[(size_t)oc * Cin + ci]);
}

__global__ __launch_bounds__(256) void prep_all(
        const float* __restrict__ wdwt, const float* __restrict__ widwt,
        const float* __restrict__ w2, const float* __restrict__ wproj,
        const float* __restrict__ w1,
        short* __restrict__ wF1, short* __restrict__ wF2c, short* __restrict__ wFk,
        short* __restrict__ wpF, short* __restrict__ wFq, float* __restrict__ scr) {
    int blk = blockIdx.x;
    int tid = threadIdx.x;
    if (blk < 2560) {
        prep3_body(wdwt, wF1, 256, blk * 256 + tid);
    } else if (blk < 2720) {
        prep3_body(widwt, wF2c, 64, (blk - 2560) * 256 + tid);
    } else if (blk < 2976) {
        prep1_body(w2, wFk, 256, 0, 8, (blk - 2720) * 256 + tid);
    } else if (blk < 2992) {
        prep1_body(wproj, wpF, 128, 64, 2, (blk - 2976) * 256 + tid);
    } else if (blk < 3008) {
        prep1_body(w1, wFq, 64, 0, 2, (blk - 2992) * 256 + tid);
    } else {
        for (int i = tid; i < 4864; i += 256) scr[i] = 0.f;
    }
}

// =================== fused Haar DWT + Q conv ===================
// grid (2 xh, 128 y2, 2 b). Block stages x rows {2y2, 2y2+1}, cols [xh*128, +128), all 64 ch
// into LDS bf16 [r*128+xl][72-padded]. Then: Q-MFMA (64oc x 256px) + Haar butterfly -> D0.
__global__ __launch_bounds__(256) void dwtq_kernel(
        const float* __restrict__ x, const short* __restrict__ wFq,
        const float* __restrict__ b1, short* __restrict__ d0, short* __restrict__ outQ) {
    __shared__ short ls[256 * 72];
    int tid = threadIdx.x;
    int lane = tid & 63, wv = tid >> 6;
    int q = lane >> 4, pl = lane & 15;
    int xh = blockIdx.x;
    int y2 = blockIdx.y;
    int b = blockIdx.z;
    int x0 = xh * 128;

    // stage: lane = channel (conflict-free LDS writes; reads L1-resident 16B/row segments)
    #pragma unroll
    for (int k2 = 0; k2 < 16; ++k2) {
        int u = k2 * 256 + tid;
        int ch = u & 63;
        int xu = (u >> 6) & 31;
        int r = (u >> 11) & 1;
        float4 v = *(const float4*)(x + (((size_t)(b * 64 + ch) * 256 + (2 * y2 + r))) * 256 + x0 + xu * 4);
        ls[(r * 128 + xu * 4 + 0) * 72 + ch] = (short)f2bs(v.x);
        ls[(r * 128 + xu * 4 + 1) * 72 + ch] = (short)f2bs(v.y);
        ls[(r * 128 + xu * 4 + 2) * 72 + ch] = (short)f2bs(v.z);
        ls[(r * 128 + xu * 4 + 3) * 72 + ch] = (short)f2bs(v.w);
    }
    __syncthreads();

    // ---- Q conv (MFMA): wave covers px p in [wv*64, wv*64+64) of the 256 staged px ----
    f32x4 acc[4][4];
    #pragma unroll
    for (int mt = 0; mt < 4; ++mt)
        #pragma unroll
        for (int nt = 0; nt < 4; ++nt)
            acc[mt][nt] = (f32x4){0.f, 0.f, 0.f, 0.f};
    #pragma unroll
    for (int chk = 0; chk < 2; ++chk) {
        short8 af[4];
        #pragma unroll
        for (int mt = 0; mt < 4; ++mt)
            af[mt] = *(const short8*)(wFq + (chk * 4 + mt) * 512 + lane * 8);
        #pragma unroll
        for (int nt = 0; nt < 4; ++nt) {
            int p = wv * 64 + nt * 16 + pl;
            short8 bfr = *(const short8*)(ls + p * 72 + chk * 32 + q * 8);
            #pragma unroll
            for (int mt = 0; mt < 4; ++mt)
                acc[mt][nt] = __builtin_amdgcn_mfma_f32_16x16x32_bf16(af[mt], bfr, acc[mt][nt], 0, 0, 0);
        }
    }
    #pragma unroll
    for (int mt = 0; mt < 4; ++mt) {
        int ocb = mt * 16 + q * 4;
        float4 bi = *(const float4*)(b1 + ocb);
        float bia[4] = {bi.x, bi.y, bi.z, bi.w};
        #pragma unroll
        for (int nt = 0; nt < 4; ++nt) {
            int p = wv * 64 + nt * 16 + pl;
            int n = (2 * y2 + (p >> 7)) * 256 + x0 + (p & 127);
            #pragma unroll
            for (int r = 0; r < 4; ++r)
                outQ[((size_t)(b * 64 + ocb + r)) * 65536 + n] = (short)f2bs(acc[mt][nt][r] + bia[r]);
        }
    }

    // ---- Haar DWT: 64 dwt px x 64 src ch -> D0 cl [b][y2][xd][256] ----
    int xl = tid >> 2;          // dwt-x local
    int cg = tid & 3;           // 16-ch group (4 lanes/xl -> contiguous 128B stores)
    int c0 = cg * 16;
    u16 obuf[4][16];
    #pragma unroll
    for (int cl = 0; cl < 16; ++cl) {
        int c = c0 + cl;
        float a  = bs2f(ls[(2 * xl) * 72 + c]);
        float bb = bs2f(ls[(2 * xl + 1) * 72 + c]);
        float c2 = bs2f(ls[(128 + 2 * xl) * 72 + c]);
        float dd = bs2f(ls[(128 + 2 * xl + 1) * 72 + c]);
        obuf[0][cl] = f2bs((a - bb + c2 - dd) * 0.5f);  // lh
        obuf[1][cl] = f2bs((a + bb - c2 - dd) * 0.5f);  // hl
        obuf[2][cl] = f2bs((a - bb - c2 + dd) * 0.5f);  // hh
        obuf[3][cl] = f2bs((a + bb + c2 + dd) * 0.5f);  // ll
    }
    int xd = xh * 64 + xl;
    size_t P = ((size_t)(b * 128 + y2) * 128 + xd) * 256;
    #pragma unroll
    for (int g = 0; g < 4; ++g) {
        *(uint4*)&d0[P + g * 64 + c0]     = pack8(&obuf[g][0]);
        *(uint4*)&d0[P + g * 64 + c0 + 8] = pack8(&obuf[g][8]);
    }
}

// =================== Haar IDWT ===================
__global__ __launch_bounds__(256) void idwt_kernel(const short* __restrict__ d1, short* __restrict__ i0) {
    int tid = threadIdx.x;
    int lane = tid & 63;
    int p = blockIdx.x * 4 + (tid >> 6);
    int b = p >> 14, m = p & 16383;
    ushort4 v = *(const ushort4*)(d1 + ((size_t)(b * 16384 + m)) * 256 + 4 * lane);
    float yl = bs2f(v.x), lh = bs2f(v.y), hl = bs2f(v.z), hh = bs2f(v.w);
    float a_ = (yl + lh + hl + hh) * 0.5f;
    float b_ = (yl - lh + hl - hh) * 0.5f;
    float c_ = (yl + lh - hl - hh) * 0.5f;
    float d_ = (yl - lh - hl + hh) * 0.5f;
    int y = m >> 7, xx = m & 127;
    u16* o = (u16*)i0;
    size_t base = ((size_t)(b * 256 + 2 * y) * 256 + 2 * xx) * 64 + lane;
    o[base] = f2bs(a_);
    o[base + 64] = f2bs(b_);
    o[base + 256 * 64] = f2bs(c_);
    o[base + 256 * 64 + 64] = f2bs(d_);
}

// =================== 3x3 conv v3: burst weight loads, input dbuf, global A-frags ===================
template <int C, int NPX, int WPG>
__global__ __launch_bounds__(256) void conv3_v3(
        const short* __restrict__ in, const short* __restrict__ wF,
        const float* __restrict__ bias, short* __restrict__ out,
        int H, int W) {
    constexpr int Wp = NPX + 2;
    constexpr int NCH = C / 16;
    constexpr int UNITS = 3 * Wp * 2;
    constexpr int UPT = (UNITS + 255) / 256;
    constexpr int BUFSZ = 3 * Wp * 16;
    extern __shared__ __align__(16) short inS[];

    int tid = threadIdx.x;
    int lane = tid & 63, wv = tid >> 6;
    int q = lane >> 4, pl = lane & 15;
    int ocg = wv / WPG;
    int pxoff = (wv % WPG) * 64;
    int x0 = blockIdx.x * NPX;
    int y = blockIdx.y;
    int b = blockIdx.z;

    int gbase[UPT];
    int ldsoff[UPT];
    #pragma unroll
    for (int k2 = 0; k2 < UPT; ++k2) {
        int u = k2 * 256 + tid;
        if (u < UNITS) {
            int r = u / (Wp * 2);
            int rem = u - r * (Wp * 2);
            int px = rem >> 1, hf = rem & 1;
            int ry = y - 1 + r;
            if (ry < 0) ry = 1;
            if (ry >= H) ry = H - 2;
            int rx = x0 - 1 + px;
            if (rx < 0) rx = 1;
            if (rx >= W) rx = W - 2;
            gbase[k2] = ((b * H + ry) * W + rx) * C + hf * 8;
            ldsoff[k2] = (r * Wp + px) * 16 + hf * 8;
        } else { gbase[k2] = 0; ldsoff[k2] = -1; }
    }

    f32x4 acc[4][4];
    #pragma unroll
    for (int mt = 0; mt < 4; ++mt)
        #pragma unroll
        for (int nt = 0; nt < 4; ++nt)
            acc[mt][nt] = (f32x4){0.f, 0.f, 0.f, 0.f};

    uint4 pf[UPT];
    #pragma unroll
    for (int k2 = 0; k2 < UPT; ++k2)
        if (ldsoff[k2] >= 0) pf[k2] = *(const uint4*)(in + gbase[k2]);
    #pragma unroll
    for (int k2 = 0; k2 < UPT; ++k2)
        if (ldsoff[k2] >= 0) *(uint4*)(inS + ldsoff[k2]) = pf[k2];
    __syncthreads();

    #pragma unroll 1
    for (int ch = 0; ch < NCH; ++ch) {
        const short* buf = inS + (ch & 1) * BUFSZ;
        short* nbuf = inS + ((ch + 1) & 1) * BUFSZ;
        bool more = (ch + 1 < NCH);
        if (more) {
            #pragma unroll
            for (int k2 = 0; k2 < UPT; ++k2)
                if (ldsoff[k2] >= 0) pf[k2] = *(const uint4*)(in + gbase[k2] + (ch + 1) * 16);
        }
        // burst-load all 20 weight fragments for this chunk (latencies overlap)
        const short* wbase = wF + ((size_t)(ocg * NCH + ch) * 5) * 2048;
        short8 wreg[5][4];
        #pragma unroll
        for (int pr = 0; pr < 5; ++pr)
            #pragma unroll
            for (int mt = 0; mt < 4; ++mt)
                wreg[pr][mt] = *(const short8*)(wbase + (pr * 4 + mt) * 512 + lane * 8);
        #pragma unroll
        for (int pr = 0; pr < 5; ++pr) {
            int t1 = 2 * pr + (q >> 1);
            if (t1 > 8) t1 = 8;
            int ti = (t1 >= 6) ? 2 : ((t1 >= 3) ? 1 : 0);
            int tj = t1 - ti * 3;
            #pragma unroll
            for (int nt = 0; nt < 4; ++nt) {
                int i = pxoff + nt * 16 + pl + tj;
                short8 bfr = *(const short8*)(buf + (ti * Wp + i) * 16 + (q & 1) * 8);
                #pragma unroll
                for (int mt = 0; mt < 4; ++mt)
                    acc[mt][nt] = __builtin_amdgcn_mfma_f32_16x16x32_bf16(wreg[pr][mt], bfr, acc[mt][nt], 0, 0, 0);
            }
        }
        if (more) {
            #pragma unroll
            for (int k2 = 0; k2 < UPT; ++k2)
                if (ldsoff[k2] >= 0) *(uint4*)(nbuf + ldsoff[k2]) = pf[k2];
            __syncthreads();
        }
    }

    #pragma unroll
    for (int mt = 0; mt < 4; ++mt) {
        int ocb = ocg * 64 + mt * 16 + q * 4;
        float4 bi = *(const float4*)(bias + ocb);
        float bia[4] = {bi.x, bi.y, bi.z, bi.w};
        #pragma unroll
        for (int nt = 0; nt < 4; ++nt) {
            int xl = x0 + pxoff + nt * 16 + pl;
            ushort4 pk;
            float v0 = acc[mt][nt][0] + bia[0]; pk.x = f2bs(v0 >= 0.f ? v0 : 0.01f * v0);
            float v1 = acc[mt][nt][1] + bia[1]; pk.y = f2bs(v1 >= 0.f ? v1 : 0.01f * v1);
            float v2 = acc[mt][nt][2] + bia[2]; pk.z = f2bs(v2 >= 0.f ? v2 : 0.01f * v2);
            float v3 = acc[mt][nt][3] + bia[3]; pk.w = f2bs(v3 >= 0.f ? v3 : 0.01f * v3);
            *(ushort4*)(out + (((size_t)(b * H + y)) * W + xl) * C + ocb) = pk;
        }
    }
}

// =================== K conv 1x1 MFMA ===================
__global__ __launch_bounds__(256) void kconv_mfma(
        const short* __restrict__ in, const short* __restrict__ wF,
        const float* __restrict__ bias, short* __restrict__ outK) {
    __shared__ short inS[8192];
    int tid = threadIdx.x;
    int lane = tid & 63, wv = tid >> 6;
    int q = lane >> 4, pl = lane & 15;
    int ocblk = blockIdx.x;
    int m0 = blockIdx.y * 256;
    int b = blockIdx.z;
    int px0w = wv * 64;
    f32x4 acc[4][4];
    #pragma unroll
    for (int mt = 0; mt < 4; ++mt)
        #pragma unroll
        for (int nt = 0; nt < 4; ++nt)
            acc[mt][nt] = (f32x4){0.f, 0.f, 0.f, 0.f};

    for (int ch = 0; ch < 8; ++ch) {
        if (ch) __syncthreads();
        const short* src = in + ((size_t)(b * 16384 + m0)) * 256 + ch * 32;
        for (int t = tid; t < 1024; t += 256) {
            int pix = t >> 2, hf = t & 3;
            *(uint4*)(inS + pix * 32 + hf * 8) = *(const uint4*)(src + (size_t)pix * 256 + hf * 8);
        }
        short8 af[4];
        #pragma unroll
        for (int mt = 0; mt < 4; ++mt)
            af[mt] = *(const short8*)(wF + ((size_t)(ocblk * 8 + ch)) * 2048 + mt * 512 + lane * 8);
        __syncthreads();
        #pragma unroll
        for (int nt = 0; nt < 4; ++nt) {
            short8 bfr = *(const short8*)(inS + (px0w + nt * 16 + pl) * 32 + q * 8);
            #pragma unroll
            for (int mt = 0; mt < 4; ++mt)
                acc[mt][nt] = __builtin_amdgcn_mfma_f32_16x16x32_bf16(af[mt], bfr, acc[mt][nt], 0, 0, 0);
        }
    }
    #pragma unroll
    for (int mt = 0; mt < 4; ++mt) {
        int ocb = ocblk * 64 + mt * 16 + q * 4;
        float4 bi = *(const float4*)(bias + ocb);
        float bia[4] = {bi.x, bi.y, bi.z, bi.w};
        #pragma unroll
        for (int nt = 0; nt < 4; ++nt) {
            int n = m0 + px0w + nt * 16 + pl;
            #pragma unroll
            for (int r = 0; r < 4; ++r) {
                int co = ocb + r;
                outK[((size_t)(b * 64 + (co >> 2))) * 65536 + (co & 3) * 16384 + n] =
                    (short)f2bs(acc[mt][nt][r] + bia[r]);
            }
        }
    }
}

// =================== Gram via MFMA: per-head 16x16 Q.K^T + row norms ===================
// grid (128 n-slices, 2 b); block = 4 waves, wave w = head w; slice n-width 512.
__global__ __launch_bounds__(256) void gram_mfma(
        const short* __restrict__ Q, const short* __restrict__ K,
        float* __restrict__ qss, float* __restrict__ kss, float* __restrict__ gram) {
    int tid = threadIdx.x;
    int lane = tid & 63, h = tid >> 6;
    int q = lane >> 4, m = lane & 15;
    int b = blockIdx.y;
    int n0 = blockIdx.x * 512;
    const short* qrow = Q + ((size_t)(b * 64 + h * 16 + m)) * 65536 + n0 + q * 8;
    const short* krow = K + ((size_t)(b * 64 + h * 16 + m)) * 65536 + n0 + q * 8;
    f32x4 acc = (f32x4){0.f, 0.f, 0.f, 0.f};
    float sq = 0.f, sk = 0.f;
    #pragma unroll 4
    for (int it = 0; it < 16; ++it) {
        short8 aq = *(const short8*)(qrow + it * 32);
        short8 ak = *(const short8*)(krow + it * 32);
        acc = __builtin_amdgcn_mfma_f32_16x16x32_bf16(aq, ak, acc, 0, 0, 0);
        #pragma unroll
        for (int j = 0; j < 8; ++j) {
            float fq = bs2f((u16)aq[j]);
            float fk = bs2f((u16)ak[j]);
            sq += fq * fq;
            sk += fk * fk;
        }
    }
    sq += __shfl_xor(sq, 16); sq += __shfl_xor(sq, 32);
    sk += __shfl_xor(sk, 16); sk += __shfl_xor(sk, 32);
    if (q == 0) {
        atomicAdd(&qss[b * 64 + h * 16 + m], sq);
        atomicAdd(&kss[b * 64 + h * 16 + m], sk);
    }
    #pragma unroll
    for (int r = 0; r < 4; ++r) {
        int c = q * 4 + r;   // row of D
        atomicAdd(&gram[b * 1024 + h * 256 + c * 16 + m], acc[r]);
    }
}

// =================== softmax(cos-sim * temp) ===================
__global__ void attn_kernel(const float* __restrict__ gram, const float* __restrict__ qss,
                            const float* __restrict__ kss, const float* __restrict__ temp,
                            float* __restrict__ attn) {
    int bh = blockIdx.x;
    int b = bh >> 2, h = bh & 3;
    int tid = threadIdx.x;
    __shared__ float L[16][17];
    __shared__ float rowmax[16], rowsum[16];
    int c = tid >> 4, d = tid & 15;
    float qn = fmaxf(sqrtf(qss[b * 64 + h * 16 + c]), 1e-12f);
    float kn = fmaxf(sqrtf(kss[b * 64 + h * 16 + d]), 1e-12f);
    float lg = gram[b * 1024 + h * 256 + c * 16 + d] / (qn * kn) * temp[h];
    L[c][d] = lg;
    __syncthreads();
    if (tid < 16) {
        float m = -1e30f;
        for (int j = 0; j < 16; ++j) m = fmaxf(m, L[tid][j]);
        rowmax[tid] = m;
    }
    __syncthreads();
    float e = expf(lg - rowmax[c]);
    L[c][d] = e;
    __syncthreads();
    if (tid < 16) {
        float s = 0.f;
        for (int j = 0; j < 16; ++j) s += L[tid][j];
        rowsum[tid] = s;
    }
    __syncthreads();
    attn[b * 1024 + h * 256 + c * 16 + d] = e / rowsum[c];
}

// =================== fold v2 ===================
__global__ __launch_bounds__(256) void fold_v2(
        const float* __restrict__ attn, const float* __restrict__ w3,
        const float* __restrict__ b3, const float* __restrict__ wproj,
        short* __restrict__ WfoldF, float* __restrict__ bfold) {
    __shared__ float attn_s[1024];
    __shared__ float wp_s[64][65];
    __shared__ float Aeff_s[64][17];
    __shared__ float beff[64];
    int bt = blockIdx.y;
    int b = bt >> 2, t = bt & 3;
    int ci0 = blockIdx.x * 16;
    int tid = threadIdx.x;
    for (int i = 0; i < 4; ++i) attn_s[tid + i * 256] = attn[b * 1024 + tid + i * 256];
    #pragma unroll
    for (int i = 0; i < 16; ++i) {
        int idx = tid + i * 256;
        int co = idx >> 6, C = idx & 63;
        wp_s[co][C] = wproj[co * 128 + C];
    }
    __syncthreads();
    #pragma unroll
    for (int pass = 0; pass < 4; ++pass) {
        int el = pass * 256 + tid;
        int C = el >> 4, ci_l = el & 15;
        int h = C >> 4, c = C & 15;
        float s = 0.f;
        #pragma unroll
        for (int d = 0; d < 16; ++d)
            s += attn_s[h * 256 + c * 16 + d] * w3[(size_t)(4 * (h * 16 + d) + t) * 256 + ci0 + ci_l];
        Aeff_s[C][ci_l] = s;
    }
    if (blockIdx.x == 0 && tid < 64) {
        int h = tid >> 4, c = tid & 15;
        float s = 0.f;
        #pragma unroll
        for (int d = 0; d < 16; ++d)
            s += attn_s[h * 256 + c * 16 + d] * b3[4 * (h * 16 + d) + t];
        beff[tid] = s;
    }
    __syncthreads();
    #pragma unroll
    for (int pass = 0; pass < 4; ++pass) {
        int el = pass * 256 + tid;
        int ci_l = el >> 6, co = el & 63;
        float s = 0.f;
        #pragma unroll
        for (int C = 0; C < 64; ++C) s += wp_s[co][C] * Aeff_s[C][ci_l];
        int ci = ci0 + ci_l;
        int chk = ci >> 5;
        int s5 = ci & 31;
        int j = s5 & 7;
        int lane2 = (((s5 >> 3) << 4)) | (co & 15);
        int mt = co >> 4;
        WfoldF[(((size_t)(bt * 8 + chk) * 4 + mt)) * 512 + lane2 * 8 + j] = (short)f2bs(s);
    }
    if (blockIdx.x == 0 && tid < 64) {
        float s = 0.f;
        #pragma unroll
        for (int C = 0; C < 64; ++C) s += wp_s[tid][C] * beff[C];
        bfold[bt * 64 + tid] = s;
    }
}

// =================== final: out = Wfold[b,t]·D1 + bfold + Wp2·I2, fp32 out ===================
__global__ __launch_bounds__(256) void final_mfma(
        const short* __restrict__ D1, const short* __restrict__ I2,
        const short* __restrict__ WfoldF, const short* __restrict__ wpF,
        const float* __restrict__ bfold, float* __restrict__ out) {
    __shared__ short inS[8192];
    int tid = threadIdx.x;
    int lane = tid & 63, wv = tid >> 6;
    int q = lane >> 4, pl = lane & 15;
    int n0 = blockIdx.x * 256;
    int b = blockIdx.y;
    int t = n0 >> 14, m0 = n0 & 16383, bt = b * 4 + t;
    int px0w = wv * 64;
    f32x4 acc[4][4];
    #pragma unroll
    for (int mt = 0; mt < 4; ++mt) {
        float4 bf4 = *(const float4*)(bfold + bt * 64 + mt * 16 + q * 4);
        #pragma unroll
        for (int nt = 0; nt < 4; ++nt)
            acc[mt][nt] = (f32x4){bf4.x, bf4.y, bf4.z, bf4.w};
    }
    for (int ch = 0; ch < 8; ++ch) {
        if (ch) __syncthreads();
        const short* src = D1 + ((size_t)(b * 16384 + m0)) * 256 + ch * 32;
        for (int tt = tid; tt < 1024; tt += 256) {
            int pix = tt >> 2, hf = tt & 3;
            *(uint4*)(inS + pix * 32 + hf * 8) = *(const uint4*)(src + (size_t)pix * 256 + hf * 8);
        }
        short8 af[4];
        #pragma unroll
        for (int mt = 0; mt < 4; ++mt)
            af[mt] = *(const short8*)(WfoldF + ((size_t)(bt * 8 + ch)) * 2048 + mt * 512 + lane * 8);
        __syncthreads();
        #pragma unroll
        for (int nt = 0; nt < 4; ++nt) {
            short8 bfr = *(const short8*)(inS + (px0w + nt * 16 + pl) * 32 + q * 8);
            #pragma unroll
            for (int mt = 0; mt < 4; ++mt)
                acc[mt][nt] = __builtin_amdgcn_mfma_f32_16x16x32_bf16(af[mt], bfr, acc[mt][nt], 0, 0, 0);
        }
    }
    for (int ch = 0; ch < 2; ++ch) {
        __syncthreads();
        const short* src = I2 + ((size_t)(b * 65536 + n0)) * 64 + ch * 32;
        for (int tt = tid; tt < 1024; tt += 256) {
            int pix = tt >> 2, hf = tt & 3;
            *(uint4*)(inS + pix * 32 + hf * 8) = *(const uint4*)(src + (size_t)pix * 64 + hf * 8);
        }
        short8 af[4];
        #pragma unroll
        for (int mt = 0; mt < 4; ++mt)
            af[mt] = *(const short8*)(wpF + (size_t)ch * 2048 + mt * 512 + lane * 8);
        __syncthreads();
        #pragma unroll
        for (int nt = 0; nt < 4; ++nt) {
            short8 bfr = *(const short8*)(inS + (px0w + nt * 16 + pl) * 32 + q * 8);
            #pragma unroll
            for (int mt = 0; mt < 4; ++mt)
                acc[mt][nt] = __builtin_amdgcn_mfma_f32_16x16x32_bf16(af[mt], bfr, acc[mt][nt], 0, 0, 0);
        }
    }
    #pragma unroll
    for (int mt = 0; mt < 4; ++mt) {
        #pragma unroll
        for (int nt = 0; nt < 4; ++nt) {
            int n = n0 + px0w + nt * 16 + pl;
            #pragma unroll
            for (int r = 0; r < 4; ++r) {
                int co = mt * 16 + q * 4 + r;
                out[((size_t)(b * 64 + co)) * 65536 + n] = acc[mt][nt][r];
            }
        }
    }
}

extern "C" void kernel_launch(void* const* d_in, const int* in_sizes, int n_in,
                              void* d_out, int out_size, void* d_ws, size_t ws_size,
                              hipStream_t stream) {
    const float* x     = (const float*)d_in[0];
    const float* temp  = (const float*)d_in[1];
    const float* w1    = (const float*)d_in[2];
    const float* b1    = (const float*)d_in[3];
    const float* w2    = (const float*)d_in[4];
    const float* b2    = (const float*)d_in[5];
    const float* w3    = (const float*)d_in[6];
    const float* b3    = (const float*)d_in[7];
    const float* wdwt  = (const float*)d_in[8];
    const float* bdwt  = (const float*)d_in[9];
    const float* widwt = (const float*)d_in[10];
    const float* bidwt = (const float*)d_in[11];
    const float* wproj = (const float*)d_in[12];
    float* out = (float*)d_out;

    char* W8 = (char*)d_ws;
    const size_t SLOT = 16777216;
    short* slotA = (short*)(W8);              // D0 -> I0
    short* slotB = (short*)(W8 + SLOT);       // D1
    short* slotC = (short*)(W8 + 2 * SLOT);   // Qb -> I2
    short* slotD = (short*)(W8 + 3 * SLOT);   // Kb
    char* P = W8 + 4 * SLOT;
    short* wF1    = (short*)P; P += 2 * 655360;
    short* wF2c   = (short*)P; P += 2 * 40960;
    short* wFk    = (short*)P; P += 2 * 65536;
    short* wpF    = (short*)P; P += 2 * 4096;
    short* wFq    = (short*)P; P += 2 * 4096;
    short* WfoldF = (short*)P; P += 2 * 131072;
    float* scr    = (float*)P;
    float* qss   = scr;
    float* kss   = scr + 128;
    float* gram  = scr + 256;
    float* attn  = scr + 2304;
    float* bfold = scr + 4352;

    prep_all<<<3009, 256, 0, stream>>>(wdwt, widwt, w2, wproj, w1,
                                       wF1, wF2c, wFk, wpF, wFq, scr);

    // fused DWT + Q conv (x read once): D0 -> slotA, Qb -> slotC
    dwtq_kernel<<<dim3(2, 128, 2), 256, 0, stream>>>(x, wFq, b1, slotA, slotC);

    // DWT-branch 3x3 conv
    conv3_v3<256, 64, 1><<<dim3(2, 128, 2), 256, 12672, stream>>>(slotA, wF1, bdwt, slotB, 128, 128);

    // K conv + gram (frees slotC after gram)
    kconv_mfma<<<dim3(4, 64, 2), 256, 0, stream>>>(slotB, wFk, b2, slotD);
    gram_mfma<<<dim3(128, 2), 256, 0, stream>>>(slotC, slotD, qss, kss, gram);

    // IDWT branch (slotA reused for I0, slotC reused for I2)
    idwt_kernel<<<8192, 256, 0, stream>>>(slotB, slotA);
    conv3_v3<64, 256, 4><<<dim3(1, 256, 2), 256, 49536, stream>>>(slotA, wF2c, bidwt, slotC, 256, 256);

    // softmax -> fold
    attn_kernel<<<8, 256, 0, stream>>>(gram, qss, kss, temp, attn);
    fold_v2<<<dim3(16, 8), 256, 0, stream>>>(attn, w3, b3, wproj, WfoldF, bfold);

    // fused (attn·V + proj) + idwt-branch proj
    final_mfma<<<dim3(256, 2), 256, 0, stream>>>(slotB, slotC, WfoldF, wpF, bfold, out);
}